// Round 6
// baseline (339.074 us; speedup 1.0000x reference)
//
#include <hip/hip_runtime.h>

typedef unsigned short u16;
typedef __attribute__((ext_vector_type(8))) unsigned short u16x8;
typedef __attribute__((ext_vector_type(8))) __bf16 bf16x8;
typedef __attribute__((ext_vector_type(4))) float f32x4;

#define M_ROWS 65536   // b*s*f
#define NQKV   1536
#define KDIM   512
#define NKT    16      // KDIM / 32

typedef __attribute__((address_space(1))) const void gconst_void;
typedef __attribute__((address_space(3))) void lds_void;

static __device__ __forceinline__ u16 f2bf(float f) {
  unsigned u = __builtin_bit_cast(unsigned, f);
  u += 0x7FFFu + ((u >> 16) & 1u);
  return (u16)(u >> 16);
}

static __device__ __forceinline__ f32x4 mfma_bf16(u16x8 a, u16x8 b, f32x4 c) {
  return __builtin_amdgcn_mfma_f32_16x16x32_bf16(
      __builtin_bit_cast(bf16x8, a), __builtin_bit_cast(bf16x8, b), c, 0, 0, 0);
}

// ---------------- fp32 -> bf16 convert (x) ----------------
__global__ void conv_x(const float* __restrict__ x, u16* __restrict__ xb) {
  const size_t t = (size_t)blockIdx.x * 256 + threadIdx.x;  // 8 elems/thread
  f32x4 a = *(const f32x4*)(x + t * 8);
  f32x4 b = *(const f32x4*)(x + t * 8 + 4);
  u16x8 w;
#pragma unroll
  for (int e = 0; e < 4; ++e) { w[e] = f2bf(a[e]); w[e + 4] = f2bf(b[e]); }
  *(u16x8*)(xb + t * 8) = w;
}

// ---------------- weight transpose+convert ----------------
__global__ void convW_qkv(const float* __restrict__ Wq, const float* __restrict__ Wk,
                          const float* __restrict__ Wv, u16* __restrict__ Wt) {
  int t = blockIdx.x * 256 + threadIdx.x;     // 0 .. 1536*512-1
  int n = t >> 9;
  int k = t & 511;
  const float* W = (n < 512) ? Wq : ((n < 1024) ? Wk : Wv);
  int col = n & 511;
  Wt[t] = f2bf(W[k * 512 + col]);             // Wt[n][k] = W[k][n]
}

__global__ void convWo(const float* __restrict__ Wo, u16* __restrict__ Wt) {
  int t = blockIdx.x * 256 + threadIdx.x;     // 0 .. 512*512-1
  int n = t >> 9;
  int k = t & 511;
  Wt[t] = f2bf(Wo[k * 512 + n]);
}

// ---------------- GEMM 256x256, BK=32, 4-deep pipelined ring --------------
// C[M][N] = A[M][K] * Bt[N][K]^T.  Same schedule as round 5 (counted vmcnt,
// 4-buffer ring, stage tile t+3 while computing tile t) but the K-loop is
// FORCED ROLLED (#pragma unroll 1): round 5's full unroll produced a
// ~40-60 KiB loop body that thrashed the 32 KiB L1-I every iteration
// (VALUBusy fell 22->14% = front-end stall signature).  Ring indices are
// runtime (t&3)*stride -- one scalar op, no unroll needed.
template <bool CF32>
__global__ __launch_bounds__(512, 2)
void gemm256(const u16* __restrict__ A, const u16* __restrict__ Bt,
             void* __restrict__ Cp, const float* __restrict__ bias,
             int N, int n_tiles) {
  __shared__ __attribute__((aligned(16))) u16 As[4][256 * 32];
  __shared__ __attribute__((aligned(16))) u16 Bs[4][256 * 32];

  const int tid  = threadIdx.x;
  const int lane = tid & 63;
  const int wid  = tid >> 6;        // 0..7
  const int wm   = wid >> 2;        // 0..1  (M half)
  const int wn   = wid & 3;         // 0..3  (N quarter)
  const int lg   = lane >> 4;       // 0..3
  const int lc   = lane & 15;

  // staging: lane l -> row l>>2 within 16-row slab, phys granule l&3;
  // source logical granule = (l&3) ^ ((row>>1)&3) = (l&3) ^ ((l>>3)&3)
  const int srow = lane >> 2;
  const int sgl  = (lane & 3) ^ ((lane >> 3) & 3);

  // ds_read: fragment row = 16*k + lc -> phys granule = lg ^ ((lc>>1)&3)
  const int gsw  = (lg ^ ((lc >> 1) & 3)) << 3;   // elem offset

  // T1: XCD-aware swizzle (grid % 8 == 0 for both GEMMs)
  const int nwg  = gridDim.x;
  const int cpx  = nwg >> 3;
  const int flat = blockIdx.x;
  const int swz  = (flat & 7) * cpx + (flat >> 3);
  const int mt   = swz / n_tiles;
  const int nt   = swz % n_tiles;
  const int row0 = mt * 256, col0 = nt * 256;

  // stage A (isB=0) or B (isB=1) of K-tile kt into ring buffer buf:
  // 2 x global_load_lds (1KB) per wave; 8 waves cover all 256 rows.
  auto stageM = [&](int isB, int buf, int kt) {
    const u16* base = isB ? Bt : A;
    const int  r0   = isB ? col0 : row0;
    u16* lbase      = isB ? &Bs[buf][0] : &As[buf][0];
#pragma unroll
    for (int c2 = 0; c2 < 2; ++c2) {
      const int R = wid * 32 + c2 * 16;           // wave-uniform row base
      const u16* src = base + (size_t)(r0 + R + srow) * KDIM + kt * 32 + sgl * 8;
      __builtin_amdgcn_global_load_lds((gconst_void*)src,
                                       (lds_void*)&lbase[R * 32], 16, 0, 0);
    }
  };

  f32x4 acc[8][4];
#pragma unroll
  for (int mi = 0; mi < 8; ++mi)
#pragma unroll
    for (int ni = 0; ni < 4; ++ni) acc[mi][ni] = (f32x4){0.f, 0.f, 0.f, 0.f};

  // prologue: fill pipeline 3 deep (12 loads/wave outstanding)
  stageM(0, 0, 0); stageM(1, 0, 0);
  stageM(0, 1, 1); stageM(1, 1, 1);
  stageM(0, 2, 2); stageM(1, 2, 2);

#pragma unroll 1
  for (int t = 0; t < NKT; ++t) {
    // tile top: ensure stage(t) landed; keep stages t+1,t+2 in flight
    if (t < NKT - 2)       asm volatile("s_waitcnt vmcnt(8)" ::: "memory");
    else if (t == NKT - 2) asm volatile("s_waitcnt vmcnt(4)" ::: "memory");
    else                   asm volatile("s_waitcnt vmcnt(0)" ::: "memory");
    __builtin_amdgcn_s_barrier();

    const u16* Asb = &As[t & 3][0];
    const u16* Bsb = &Bs[t & 3][0];
    u16x8 af0[4], af1[4], bfr[4];

    // ---- phase 0: stage A(t+3); read B + A-half0; MFMA half0 ----
    if (t + 3 < NKT) stageM(0, (t + 3) & 3, t + 3);
#pragma unroll
    for (int ni = 0; ni < 4; ++ni)
      bfr[ni] = *(const u16x8*)&Bsb[(wn * 64 + ni * 16 + lc) * 32 + gsw];
#pragma unroll
    for (int i = 0; i < 4; ++i)
      af0[i] = *(const u16x8*)&Asb[(wm * 128 + i * 16 + lc) * 32 + gsw];

    __builtin_amdgcn_s_barrier();
    asm volatile("s_waitcnt lgkmcnt(0)" ::: "memory");
    __builtin_amdgcn_sched_barrier(0);
    __builtin_amdgcn_s_setprio(1);
#pragma unroll
    for (int i = 0; i < 4; ++i)
#pragma unroll
      for (int ni = 0; ni < 4; ++ni)
        acc[i][ni] = mfma_bf16(af0[i], bfr[ni], acc[i][ni]);
    __builtin_amdgcn_s_setprio(0);
    __builtin_amdgcn_sched_barrier(0);
    __builtin_amdgcn_s_barrier();

    // ---- phase 1: stage B(t+3); read A-half1; MFMA half1 ----
    if (t + 3 < NKT) stageM(1, (t + 3) & 3, t + 3);
#pragma unroll
    for (int i = 0; i < 4; ++i)
      af1[i] = *(const u16x8*)&Asb[(wm * 128 + 64 + i * 16 + lc) * 32 + gsw];

    __builtin_amdgcn_s_barrier();
    asm volatile("s_waitcnt lgkmcnt(0)" ::: "memory");
    __builtin_amdgcn_sched_barrier(0);
    __builtin_amdgcn_s_setprio(1);
#pragma unroll
    for (int i = 0; i < 4; ++i)
#pragma unroll
      for (int ni = 0; ni < 4; ++ni)
        acc[4 + i][ni] = mfma_bf16(af1[i], bfr[ni], acc[4 + i][ni]);
    __builtin_amdgcn_s_setprio(0);
    __builtin_amdgcn_sched_barrier(0);
    // next tile-top vmcnt+barrier closes this phase
  }

  // epilogue
  const int gmb = row0 + wm * 128;
  const int gnb = col0 + wn * 64;
#pragma unroll
  for (int mi = 0; mi < 8; ++mi)
#pragma unroll
    for (int ni = 0; ni < 4; ++ni) {
      const int gm = gmb + mi * 16 + lg * 4;
      const int gn = gnb + ni * 16 + lc;
      f32x4 v = acc[mi][ni];
      if constexpr (CF32) {
        float* C = (float*)Cp;
        float bv = bias[gn];
#pragma unroll
        for (int r = 0; r < 4; ++r) C[(size_t)(gm + r) * N + gn] = v[r] + bv;
      } else {
        u16* C = (u16*)Cp;
#pragma unroll
        for (int r = 0; r < 4; ++r) C[(size_t)(gm + r) * N + gn] = f2bf(v[r]);
      }
    }
}

// ---------------- attention over frames (f=16) ----------------
__global__ __launch_bounds__(256, 4)
void attn_kernel(const u16* __restrict__ qkv, const float* __restrict__ pos_bias,
                 u16* __restrict__ attn) {
  __shared__ __attribute__((aligned(16))) u16 P_lds[4 * 256];
  const int tid  = threadIdx.x;
  const int lane = tid & 63;
  const int wv   = tid >> 6;
  const int bs   = blockIdx.x;
  const int lg   = lane >> 4;
  const int lc   = lane & 15;
  const float scale = 0.125f;   // 1/sqrt(64)
  const f32x4 zf = {0.f, 0.f, 0.f, 0.f};

  for (int hh = 0; hh < 2; ++hh) {
    const int h = wv * 2 + hh;
    const size_t rowb = (size_t)(bs * 16 + lc) * NQKV;

    u16x8 aq0 = *(const u16x8*)(qkv + rowb + h * 64 + 0 * 32 + lg * 8);
    u16x8 aq1 = *(const u16x8*)(qkv + rowb + h * 64 + 1 * 32 + lg * 8);
    u16x8 bk0 = *(const u16x8*)(qkv + rowb + 512 + h * 64 + 0 * 32 + lg * 8);
    u16x8 bk1 = *(const u16x8*)(qkv + rowb + 512 + h * 64 + 1 * 32 + lg * 8);
    f32x4 s = mfma_bf16(aq0, bk0, zf);
    s = mfma_bf16(aq1, bk1, s);

#pragma unroll
    for (int r = 0; r < 4; ++r) {
      const int i = lg * 4 + r;
      float sv = s[r] * scale + pos_bias[h * 256 + i * 16 + lc];
      if (lc > i) sv = -1e30f;
      float m = sv;
#pragma unroll
      for (int off = 8; off >= 1; off >>= 1) m = fmaxf(m, __shfl_xor(m, off));
      float e = __expf(sv - m);
      float sm = e;
#pragma unroll
      for (int off = 8; off >= 1; off >>= 1) sm += __shfl_xor(sm, off);
      P_lds[wv * 256 + i * 16 + lc] = f2bf(e / sm);
    }
    asm volatile("s_waitcnt lgkmcnt(0)" ::: "memory");

    u16x8 ap = {0, 0, 0, 0, 0, 0, 0, 0};
    if (lane < 32) ap = *(const u16x8*)&P_lds[wv * 256 + lc * 16 + lg * 8];

#pragma unroll
    for (int nd = 0; nd < 4; ++nd) {
      u16x8 bv = {0, 0, 0, 0, 0, 0, 0, 0};
      if (lane < 32) {
#pragma unroll
        for (int jj = 0; jj < 8; ++jj) {
          int j = lg * 8 + jj;
          bv[jj] = qkv[(size_t)(bs * 16 + j) * NQKV + 1024 + h * 64 + nd * 16 + lc];
        }
      }
      f32x4 o = mfma_bf16(ap, bv, zf);
#pragma unroll
      for (int r = 0; r < 4; ++r) {
        const int i = lg * 4 + r;
        attn[(size_t)(bs * 16 + i) * 512 + h * 64 + nd * 16 + lc] = f2bf(o[r]);
      }
    }
  }
}

// ---------------- launch ----------------
extern "C" void kernel_launch(void* const* d_in, const int* in_sizes, int n_in,
                              void* d_out, int out_size, void* d_ws, size_t ws_size,
                              hipStream_t stream) {
  const float* x        = (const float*)d_in[0];
  const float* pos_bias = (const float*)d_in[1];
  const float* Wq       = (const float*)d_in[2];
  const float* Wk       = (const float*)d_in[3];
  const float* Wv       = (const float*)d_in[4];
  const float* Wo       = (const float*)d_in[5];
  const float* bo       = (const float*)d_in[6];
  float* out            = (float*)d_out;

  // ws layout (256 MiB budget):
  //   [0,   64 MiB): xb (bf16 x) -> reused as attnbuf after GEMM1
  //   [64, 256 MiB): qkv (bf16)  -> reused for Wo_t after attention
  // Wqkv_t (1.5 MiB) lives in d_out (fully overwritten by GEMM2 at the end).
  u16* xb      = (u16*)d_ws;                           // [65536][512]
  u16* qkv     = xb + (size_t)M_ROWS * 512;            // [65536][1536]
  u16* attnbuf = xb;                                   // [65536][512]
  u16* Wqkv_t  = (u16*)d_out;                          // [1536][512]
  u16* Wo_t    = qkv;                                  // [512][512]

  // 1) x -> bf16
  conv_x<<<dim3(M_ROWS * KDIM / (256 * 8)), dim3(256), 0, stream>>>(x, xb);

  // 2) Wq|Wk|Wv -> Wqkv_t[1536][512] bf16 (in d_out)
  convW_qkv<<<dim3(3072), dim3(256), 0, stream>>>(Wq, Wk, Wv, Wqkv_t);

  // 3) qkv = xb @ Wqkv  (M=65536, N=1536, K=512): 256x6 tiles = 1536 blocks
  gemm256<false><<<dim3(1536), dim3(512), 0, stream>>>(
      xb, Wqkv_t, (void*)qkv, (const float*)nullptr, NQKV, 6);

  // 4) attention -> attnbuf (overwrites xb: dead)
  attn_kernel<<<dim3(4096), dim3(256), 0, stream>>>(qkv, pos_bias, attnbuf);

  // 5) Wo -> Wo_t (in dead qkv region)
  convWo<<<dim3(1024), dim3(256), 0, stream>>>(Wo, Wo_t);

  // 6) out = attnbuf @ Wo + bo  (M=65536, N=512, K=512): 256x2 tiles = 512 blocks
  gemm256<true><<<dim3(512), dim3(512), 0, stream>>>(
      attnbuf, Wo_t, (void*)out, bo, 512, 2);
}

// Round 7
// 320.093 us; speedup vs baseline: 1.0593x; 1.0593x over previous
//
#include <hip/hip_runtime.h>

typedef unsigned short u16;
typedef __attribute__((ext_vector_type(8))) unsigned short u16x8;
typedef __attribute__((ext_vector_type(8))) __bf16 bf16x8;
typedef __attribute__((ext_vector_type(4))) float f32x4;

#define M_ROWS 65536   // b*s*f
#define NQKV   1536
#define KDIM   512
#define NKT    8       // KDIM / 64

typedef __attribute__((address_space(1))) const void gconst_void;
typedef __attribute__((address_space(3))) void lds_void;

static __device__ __forceinline__ u16 f2bf(float f) {
  unsigned u = __builtin_bit_cast(unsigned, f);
  u += 0x7FFFu + ((u >> 16) & 1u);
  return (u16)(u >> 16);
}

static __device__ __forceinline__ f32x4 mfma_bf16(u16x8 a, u16x8 b, f32x4 c) {
  return __builtin_amdgcn_mfma_f32_16x16x32_bf16(
      __builtin_bit_cast(bf16x8, a), __builtin_bit_cast(bf16x8, b), c, 0, 0, 0);
}

// ---------------- fp32 -> bf16 convert (x) ----------------
__global__ void conv_x(const float* __restrict__ x, u16* __restrict__ xb) {
  const size_t t = (size_t)blockIdx.x * 256 + threadIdx.x;  // 8 elems/thread
  f32x4 a = *(const f32x4*)(x + t * 8);
  f32x4 b = *(const f32x4*)(x + t * 8 + 4);
  u16x8 w;
#pragma unroll
  for (int e = 0; e < 4; ++e) { w[e] = f2bf(a[e]); w[e + 4] = f2bf(b[e]); }
  *(u16x8*)(xb + t * 8) = w;
}

// ---------------- weight transpose+convert ----------------
__global__ void convW_qkv(const float* __restrict__ Wq, const float* __restrict__ Wk,
                          const float* __restrict__ Wv, u16* __restrict__ Wt) {
  int t = blockIdx.x * 256 + threadIdx.x;     // 0 .. 1536*512-1
  int n = t >> 9;
  int k = t & 511;
  const float* W = (n < 512) ? Wq : ((n < 1024) ? Wk : Wv);
  int col = n & 511;
  Wt[t] = f2bf(W[k * 512 + col]);             // Wt[n][k] = W[k][n]
}

__global__ void convWo(const float* __restrict__ Wo, u16* __restrict__ Wt) {
  int t = blockIdx.x * 256 + threadIdx.x;     // 0 .. 512*512-1
  int n = t >> 9;
  int k = t & 511;
  Wt[t] = f2bf(Wo[k * 512 + n]);
}

// ---------------- GEMM 256x256, BK=64, counted-vmcnt k-slice pipeline -----
// C[M][N] = A[M][K] * Bt[N][K]^T.  Round-3 structure (4 phases/K-tile, 2
// gload_lds + 4-8 ds_read + 16 MFMA per phase, 2 dbuf) with ONE change:
// counted boundary waits.  LDS is k-slice-major [buf][ks][256][32]; stage
// order per tile t (for t+1): A-ks0, B-ks0, A-ks1, B-ks1 (one stage/phase).
// Tile-top wait = vmcnt(4): retires the ks0 pair (needed by phases 0-1),
// leaves the ks1 pair in flight.  Mid-tile wait = vmcnt(4): retires the ks1
// pair, leaves t+1's first two stages in flight.  Never drain-0 until the
// last tile.  Per-wave wait + barrier collectivizes across waves.
template <bool CF32>
__global__ __launch_bounds__(512, 2)
void gemm256(const u16* __restrict__ A, const u16* __restrict__ Bt,
             void* __restrict__ Cp, const float* __restrict__ bias,
             int N, int n_tiles) {
  __shared__ __attribute__((aligned(16))) u16 As[2][2][256 * 32];
  __shared__ __attribute__((aligned(16))) u16 Bs[2][2][256 * 32];

  const int tid  = threadIdx.x;
  const int lane = tid & 63;
  const int wid  = tid >> 6;        // 0..7
  const int wm   = wid >> 2;        // 0..1  (M half)
  const int wn   = wid & 3;         // 0..3  (N quarter)
  const int lg   = lane >> 4;       // 0..3
  const int lc   = lane & 15;

  // staging: lane l -> row l>>2 within 16-row slab, phys granule l&3;
  // source logical granule = (l&3) ^ ((row>>1)&3) = (l&3) ^ ((l>>3)&3)
  const int srow = lane >> 2;
  const int sgl  = (lane & 3) ^ ((lane >> 3) & 3);

  // ds_read: fragment row ≡ lc (mod 16) -> phys granule = lg ^ ((lc>>1)&3)
  const int gsw  = (lg ^ ((lc >> 1) & 3)) << 3;   // elem offset within slice row

  // T1: XCD-aware swizzle (grid % 8 == 0 for both GEMMs)
  const int nwg  = gridDim.x;
  const int cpx  = nwg >> 3;
  const int flat = blockIdx.x;
  const int swz  = (flat & 7) * cpx + (flat >> 3);
  const int mt   = swz / n_tiles;
  const int nt   = swz % n_tiles;
  const int row0 = mt * 256, col0 = nt * 256;

  // stage one k-slice (32 cols) of A (isB=0) or B (isB=1), K-tile kt, into
  // buffer buf: 2 x global_load_lds (1KB) per wave; 8 waves cover 256 rows.
  auto stageKS = [&](int isB, int buf, int ks, int kt) {
    const u16* base = isB ? Bt : A;
    const int  r0   = isB ? col0 : row0;
    u16* lbase      = isB ? &Bs[buf][ks][0] : &As[buf][ks][0];
#pragma unroll
    for (int c2 = 0; c2 < 2; ++c2) {
      const int R = wid * 32 + c2 * 16;           // wave-uniform row base
      const u16* src = base + (size_t)(r0 + R + srow) * KDIM + kt * 64 + ks * 32 + sgl * 8;
      __builtin_amdgcn_global_load_lds((gconst_void*)src,
                                       (lds_void*)&lbase[R * 32], 16, 0, 0);
    }
  };

  f32x4 acc[8][4];
#pragma unroll
  for (int mi = 0; mi < 8; ++mi)
#pragma unroll
    for (int ni = 0; ni < 4; ++ni) acc[mi][ni] = (f32x4){0.f, 0.f, 0.f, 0.f};

  // prologue: stage tile 0 (order must match steady state: Aks0,Bks0,Aks1,Bks1)
  stageKS(0, 0, 0, 0); stageKS(1, 0, 0, 0); stageKS(0, 0, 1, 0); stageKS(1, 0, 1, 0);

  for (int t = 0; t < NKT; ++t) {
    const int  c   = t & 1;
    const bool pre = (t + 1) < NKT;
    const u16* A0 = &As[c][0][0], *A1 = &As[c][1][0];
    const u16* B0 = &Bs[c][0][0], *B1 = &Bs[c][1][0];
    u16x8 af[4], bfr[4];

    // ---- tile top: ks0 pair landed; ks1 pair may fly ----
    asm volatile("s_waitcnt vmcnt(4)" ::: "memory");
    __builtin_amdgcn_s_barrier();

    // ---- P0 (ks0, mh0): stage A-ks0(t+1) ----
    if (pre) stageKS(0, c ^ 1, 0, t + 1);
#pragma unroll
    for (int ni = 0; ni < 4; ++ni)
      bfr[ni] = *(const u16x8*)&B0[(wn * 64 + ni * 16 + lc) * 32 + gsw];
#pragma unroll
    for (int i = 0; i < 4; ++i)
      af[i] = *(const u16x8*)&A0[(wm * 128 + i * 16 + lc) * 32 + gsw];
    __builtin_amdgcn_s_barrier();
    asm volatile("s_waitcnt lgkmcnt(0)" ::: "memory");
    __builtin_amdgcn_sched_barrier(0);
    __builtin_amdgcn_s_setprio(1);
#pragma unroll
    for (int i = 0; i < 4; ++i)
#pragma unroll
      for (int ni = 0; ni < 4; ++ni)
        acc[i][ni] = mfma_bf16(af[i], bfr[ni], acc[i][ni]);
    __builtin_amdgcn_s_setprio(0);
    __builtin_amdgcn_sched_barrier(0);
    __builtin_amdgcn_s_barrier();

    // ---- P1 (ks0, mh1): stage B-ks0(t+1) ----
    if (pre) stageKS(1, c ^ 1, 0, t + 1);
#pragma unroll
    for (int i = 0; i < 4; ++i)
      af[i] = *(const u16x8*)&A0[(wm * 128 + 64 + i * 16 + lc) * 32 + gsw];
    __builtin_amdgcn_s_barrier();
    asm volatile("s_waitcnt lgkmcnt(0)" ::: "memory");
    __builtin_amdgcn_sched_barrier(0);
    __builtin_amdgcn_s_setprio(1);
#pragma unroll
    for (int i = 0; i < 4; ++i)
#pragma unroll
      for (int ni = 0; ni < 4; ++ni)
        acc[4 + i][ni] = mfma_bf16(af[i], bfr[ni], acc[4 + i][ni]);
    __builtin_amdgcn_s_setprio(0);
    __builtin_amdgcn_sched_barrier(0);

    // ---- mid-tile: ks1 pair landed; t+1's first two stages may fly ----
    if (pre) asm volatile("s_waitcnt vmcnt(4)" ::: "memory");
    else     asm volatile("s_waitcnt vmcnt(0)" ::: "memory");
    __builtin_amdgcn_s_barrier();

    // ---- P2 (ks1, mh0): stage A-ks1(t+1) ----
    if (pre) stageKS(0, c ^ 1, 1, t + 1);
#pragma unroll
    for (int ni = 0; ni < 4; ++ni)
      bfr[ni] = *(const u16x8*)&B1[(wn * 64 + ni * 16 + lc) * 32 + gsw];
#pragma unroll
    for (int i = 0; i < 4; ++i)
      af[i] = *(const u16x8*)&A1[(wm * 128 + i * 16 + lc) * 32 + gsw];
    __builtin_amdgcn_s_barrier();
    asm volatile("s_waitcnt lgkmcnt(0)" ::: "memory");
    __builtin_amdgcn_sched_barrier(0);
    __builtin_amdgcn_s_setprio(1);
#pragma unroll
    for (int i = 0; i < 4; ++i)
#pragma unroll
      for (int ni = 0; ni < 4; ++ni)
        acc[i][ni] = mfma_bf16(af[i], bfr[ni], acc[i][ni]);
    __builtin_amdgcn_s_setprio(0);
    __builtin_amdgcn_sched_barrier(0);
    __builtin_amdgcn_s_barrier();

    // ---- P3 (ks1, mh1): stage B-ks1(t+1) ----
    if (pre) stageKS(1, c ^ 1, 1, t + 1);
#pragma unroll
    for (int i = 0; i < 4; ++i)
      af[i] = *(const u16x8*)&A1[(wm * 128 + 64 + i * 16 + lc) * 32 + gsw];
    __builtin_amdgcn_s_barrier();
    asm volatile("s_waitcnt lgkmcnt(0)" ::: "memory");
    __builtin_amdgcn_sched_barrier(0);
    __builtin_amdgcn_s_setprio(1);
#pragma unroll
    for (int i = 0; i < 4; ++i)
#pragma unroll
      for (int ni = 0; ni < 4; ++ni)
        acc[4 + i][ni] = mfma_bf16(af[i], bfr[ni], acc[4 + i][ni]);
    __builtin_amdgcn_s_setprio(0);
    __builtin_amdgcn_sched_barrier(0);
    // loop top provides vmcnt(4) + barrier
  }

  // epilogue
  const int gmb = row0 + wm * 128;
  const int gnb = col0 + wn * 64;
#pragma unroll
  for (int mi = 0; mi < 8; ++mi)
#pragma unroll
    for (int ni = 0; ni < 4; ++ni) {
      const int gm = gmb + mi * 16 + lg * 4;
      const int gn = gnb + ni * 16 + lc;
      f32x4 v = acc[mi][ni];
      if constexpr (CF32) {
        float* C = (float*)Cp;
        float bv = bias[gn];
#pragma unroll
        for (int r = 0; r < 4; ++r) C[(size_t)(gm + r) * N + gn] = v[r] + bv;
      } else {
        u16* C = (u16*)Cp;
#pragma unroll
        for (int r = 0; r < 4; ++r) C[(size_t)(gm + r) * N + gn] = f2bf(v[r]);
      }
    }
}

// ---------------- attention over frames (f=16) ----------------
__global__ __launch_bounds__(256, 4)
void attn_kernel(const u16* __restrict__ qkv, const float* __restrict__ pos_bias,
                 u16* __restrict__ attn) {
  __shared__ __attribute__((aligned(16))) u16 P_lds[4 * 256];
  const int tid  = threadIdx.x;
  const int lane = tid & 63;
  const int wv   = tid >> 6;
  const int bs   = blockIdx.x;
  const int lg   = lane >> 4;
  const int lc   = lane & 15;
  const float scale = 0.125f;   // 1/sqrt(64)
  const f32x4 zf = {0.f, 0.f, 0.f, 0.f};

  for (int hh = 0; hh < 2; ++hh) {
    const int h = wv * 2 + hh;
    const size_t rowb = (size_t)(bs * 16 + lc) * NQKV;

    u16x8 aq0 = *(const u16x8*)(qkv + rowb + h * 64 + 0 * 32 + lg * 8);
    u16x8 aq1 = *(const u16x8*)(qkv + rowb + h * 64 + 1 * 32 + lg * 8);
    u16x8 bk0 = *(const u16x8*)(qkv + rowb + 512 + h * 64 + 0 * 32 + lg * 8);
    u16x8 bk1 = *(const u16x8*)(qkv + rowb + 512 + h * 64 + 1 * 32 + lg * 8);
    f32x4 s = mfma_bf16(aq0, bk0, zf);
    s = mfma_bf16(aq1, bk1, s);

#pragma unroll
    for (int r = 0; r < 4; ++r) {
      const int i = lg * 4 + r;
      float sv = s[r] * scale + pos_bias[h * 256 + i * 16 + lc];
      if (lc > i) sv = -1e30f;
      float m = sv;
#pragma unroll
      for (int off = 8; off >= 1; off >>= 1) m = fmaxf(m, __shfl_xor(m, off));
      float e = __expf(sv - m);
      float sm = e;
#pragma unroll
      for (int off = 8; off >= 1; off >>= 1) sm += __shfl_xor(sm, off);
      P_lds[wv * 256 + i * 16 + lc] = f2bf(e / sm);
    }
    asm volatile("s_waitcnt lgkmcnt(0)" ::: "memory");

    u16x8 ap = {0, 0, 0, 0, 0, 0, 0, 0};
    if (lane < 32) ap = *(const u16x8*)&P_lds[wv * 256 + lc * 16 + lg * 8];

#pragma unroll
    for (int nd = 0; nd < 4; ++nd) {
      u16x8 bv = {0, 0, 0, 0, 0, 0, 0, 0};
      if (lane < 32) {
#pragma unroll
        for (int jj = 0; jj < 8; ++jj) {
          int j = lg * 8 + jj;
          bv[jj] = qkv[(size_t)(bs * 16 + j) * NQKV + 1024 + h * 64 + nd * 16 + lc];
        }
      }
      f32x4 o = mfma_bf16(ap, bv, zf);
#pragma unroll
      for (int r = 0; r < 4; ++r) {
        const int i = lg * 4 + r;
        attn[(size_t)(bs * 16 + i) * 512 + h * 64 + nd * 16 + lc] = f2bf(o[r]);
      }
    }
  }
}

// ---------------- launch ----------------
extern "C" void kernel_launch(void* const* d_in, const int* in_sizes, int n_in,
                              void* d_out, int out_size, void* d_ws, size_t ws_size,
                              hipStream_t stream) {
  const float* x        = (const float*)d_in[0];
  const float* pos_bias = (const float*)d_in[1];
  const float* Wq       = (const float*)d_in[2];
  const float* Wk       = (const float*)d_in[3];
  const float* Wv       = (const float*)d_in[4];
  const float* Wo       = (const float*)d_in[5];
  const float* bo       = (const float*)d_in[6];
  float* out            = (float*)d_out;

  // ws layout (256 MiB budget):
  //   [0,   64 MiB): xb (bf16 x) -> reused as attnbuf after GEMM1
  //   [64, 256 MiB): qkv (bf16)  -> reused for Wo_t after attention
  // Wqkv_t (1.5 MiB) lives in d_out (fully overwritten by GEMM2 at the end).
  u16* xb      = (u16*)d_ws;                           // [65536][512]
  u16* qkv     = xb + (size_t)M_ROWS * 512;            // [65536][1536]
  u16* attnbuf = xb;                                   // [65536][512]
  u16* Wqkv_t  = (u16*)d_out;                          // [1536][512]
  u16* Wo_t    = qkv;                                  // [512][512]

  // 1) x -> bf16
  conv_x<<<dim3(M_ROWS * KDIM / (256 * 8)), dim3(256), 0, stream>>>(x, xb);

  // 2) Wq|Wk|Wv -> Wqkv_t[1536][512] bf16 (in d_out)
  convW_qkv<<<dim3(3072), dim3(256), 0, stream>>>(Wq, Wk, Wv, Wqkv_t);

  // 3) qkv = xb @ Wqkv  (M=65536, N=1536, K=512): 256x6 tiles = 1536 blocks
  gemm256<false><<<dim3(1536), dim3(512), 0, stream>>>(
      xb, Wqkv_t, (void*)qkv, (const float*)nullptr, NQKV, 6);

  // 4) attention -> attnbuf (overwrites xb: dead)
  attn_kernel<<<dim3(4096), dim3(256), 0, stream>>>(qkv, pos_bias, attnbuf);

  // 5) Wo -> Wo_t (in dead qkv region)
  convWo<<<dim3(1024), dim3(256), 0, stream>>>(Wo, Wo_t);

  // 6) out = attnbuf @ Wo + bo  (M=65536, N=512, K=512): 256x2 tiles = 512 blocks
  gemm256<true><<<dim3(512), dim3(512), 0, stream>>>(
      attnbuf, Wo_t, (void*)out, bo, 512, 2);
}

// Round 8
// 304.626 us; speedup vs baseline: 1.1131x; 1.0508x over previous
//
#include <hip/hip_runtime.h>

typedef unsigned short u16;
typedef __attribute__((ext_vector_type(8))) unsigned short u16x8;
typedef __attribute__((ext_vector_type(8))) __bf16 bf16x8;
typedef __attribute__((ext_vector_type(4))) float f32x4;

#define M_ROWS 65536   // b*s*f
#define NQKV   1536
#define KDIM   512

typedef __attribute__((address_space(1))) const void gconst_void;
typedef __attribute__((address_space(3))) void lds_void;

static __device__ __forceinline__ u16 f2bf(float f) {
  unsigned u = __builtin_bit_cast(unsigned, f);
  u += 0x7FFFu + ((u >> 16) & 1u);
  return (u16)(u >> 16);
}

static __device__ __forceinline__ f32x4 mfma_bf16(u16x8 a, u16x8 b, f32x4 c) {
  return __builtin_amdgcn_mfma_f32_16x16x32_bf16(
      __builtin_bit_cast(bf16x8, a), __builtin_bit_cast(bf16x8, b), c, 0, 0, 0);
}

// ---------------- fp32 -> bf16 convert (x) ----------------
__global__ void conv_x(const float* __restrict__ x, u16* __restrict__ xb) {
  const size_t t = (size_t)blockIdx.x * 256 + threadIdx.x;  // 8 elems/thread
  f32x4 a = *(const f32x4*)(x + t * 8);
  f32x4 b = *(const f32x4*)(x + t * 8 + 4);
  u16x8 w;
#pragma unroll
  for (int e = 0; e < 4; ++e) { w[e] = f2bf(a[e]); w[e + 4] = f2bf(b[e]); }
  *(u16x8*)(xb + t * 8) = w;
}

// ---------------- weight transpose+convert ----------------
__global__ void convW_qkv(const float* __restrict__ Wq, const float* __restrict__ Wk,
                          const float* __restrict__ Wv, u16* __restrict__ Wt) {
  int t = blockIdx.x * 256 + threadIdx.x;     // 0 .. 1536*512-1
  int n = t >> 9;
  int k = t & 511;
  const float* W = (n < 512) ? Wq : ((n < 1024) ? Wk : Wv);
  int col = n & 511;
  Wt[t] = f2bf(W[k * 512 + col]);             // Wt[n][k] = W[k][n]
}

__global__ void convWo(const float* __restrict__ Wo, u16* __restrict__ Wt) {
  int t = blockIdx.x * 256 + threadIdx.x;     // 0 .. 512*512-1
  int n = t >> 9;
  int k = t & 511;
  Wt[t] = f2bf(Wo[k * 512 + n]);
}

// ---------------- GEMM 128x128, BK=32, occupancy-first ----------------
// C[M][N] = A[M][K] * Bt[N][K]^T.  Round-2's proven m97 structure
// (global_load_lds width-16, 2-deep dbuf, one __syncthreads-style drain per
// K-step) with two deltas:
//  (a) granule XOR-swizzle g^((row>>1)&3) -- source-side on staging,
//      read-side on fragments (involution, rule #21) -> r2's 8-way ds_read
//      conflict becomes 2-way (free per m136).
//  (b) 32 KiB LDS + __launch_bounds__(256,4) -> 4-5 blocks/CU resident;
//      cross-block wave overlap (m114) hides staging latency -- the lever
//      the 1-block/CU 256^2 variants (r3-r7) structurally lacked.
template <bool CF32>
__global__ __launch_bounds__(256, 4)
void gemm128(const u16* __restrict__ A, const u16* __restrict__ Bt,
             void* __restrict__ Cp, const float* __restrict__ bias,
             int N, int K, int n_tiles) {
  __shared__ __attribute__((aligned(16))) u16 As[2][128 * 32];
  __shared__ __attribute__((aligned(16))) u16 Bs[2][128 * 32];

  const int tid  = threadIdx.x;
  const int lane = tid & 63;
  const int wv   = tid >> 6;        // 0..3
  const int wm   = wv >> 1, wn = wv & 1;
  const int lg   = lane >> 4;       // 0..3
  const int lc   = lane & 15;

  // staging: wave wv stages segments {2wv, 2wv+1} (16 rows x 32 cols each);
  // lane l -> row l>>2, phys granule l&3; source granule pre-swizzled:
  const int srow = lane >> 2;                       // 0..15
  const int sgl  = (lane & 3) ^ ((lane >> 3) & 3);  // (l&3) ^ ((row>>1)&3)
  const int seg  = wv * 2;

  // fragment ds_read: row = mi*16+lc, phys granule = lg ^ ((lc>>1)&3)
  const int gsw  = (lg ^ ((lc >> 1) & 3)) << 3;     // elem offset

  // T1: XCD-aware swizzle (grid % 8 == 0 for both GEMMs)
  const int nwg  = gridDim.x;
  const int cpx  = nwg >> 3;
  const int flat = blockIdx.x;
  const int swz  = (flat & 7) * cpx + (flat >> 3);
  const int mt   = swz / n_tiles;
  const int nt   = swz % n_tiles;
  const int row0 = mt * 128, col0 = nt * 128;

  auto stage = [&](int buf, int kt) {
    const int k0 = kt * 32;
#pragma unroll
    for (int p = 0; p < 2; ++p) {
      const int s = seg + p;
      const u16* ga = A  + (size_t)(row0 + s * 16 + srow) * K + k0 + sgl * 8;
      const u16* gb = Bt + (size_t)(col0 + s * 16 + srow) * K + k0 + sgl * 8;
      __builtin_amdgcn_global_load_lds((gconst_void*)ga, (lds_void*)&As[buf][s * 512], 16, 0, 0);
      __builtin_amdgcn_global_load_lds((gconst_void*)gb, (lds_void*)&Bs[buf][s * 512], 16, 0, 0);
    }
  };

  f32x4 acc[4][4];
#pragma unroll
  for (int mi = 0; mi < 4; ++mi)
#pragma unroll
    for (int ni = 0; ni < 4; ++ni) acc[mi][ni] = (f32x4){0.f, 0.f, 0.f, 0.f};

  const int nkt = K >> 5;   // 16
  stage(0, 0);
  __syncthreads();

  int cur = 0;
  for (int kt = 0; kt < nkt; ++kt) {
    if (kt + 1 < nkt) stage(cur ^ 1, kt + 1);   // in flight across ds_read+MFMA

    u16x8 af[4], bfr[4];
#pragma unroll
    for (int mi = 0; mi < 4; ++mi)
      af[mi] = *(const u16x8*)&As[cur][(wm * 64 + mi * 16 + lc) * 32 + gsw];
#pragma unroll
    for (int ni = 0; ni < 4; ++ni)
      bfr[ni] = *(const u16x8*)&Bs[cur][(wn * 64 + ni * 16 + lc) * 32 + gsw];
#pragma unroll
    for (int mi = 0; mi < 4; ++mi)
#pragma unroll
      for (int ni = 0; ni < 4; ++ni)
        acc[mi][ni] = mfma_bf16(af[mi], bfr[ni], acc[mi][ni]);

    __syncthreads();   // drains vmcnt+lgkm, then barrier (proven r2 form)
    cur ^= 1;
  }

  // epilogue
  const int gmb = row0 + wm * 64;
  const int gnb = col0 + wn * 64;
#pragma unroll
  for (int mi = 0; mi < 4; ++mi)
#pragma unroll
    for (int ni = 0; ni < 4; ++ni) {
      const int gm = gmb + mi * 16 + lg * 4;
      const int gn = gnb + ni * 16 + lc;
      f32x4 v = acc[mi][ni];
      if constexpr (CF32) {
        float* C = (float*)Cp;
        float bv = bias[gn];
#pragma unroll
        for (int r = 0; r < 4; ++r) C[(size_t)(gm + r) * N + gn] = v[r] + bv;
      } else {
        u16* C = (u16*)Cp;
#pragma unroll
        for (int r = 0; r < 4; ++r) C[(size_t)(gm + r) * N + gn] = f2bf(v[r]);
      }
    }
}

// ---------------- attention over frames (f=16) ----------------
__global__ __launch_bounds__(256, 4)
void attn_kernel(const u16* __restrict__ qkv, const float* __restrict__ pos_bias,
                 u16* __restrict__ attn) {
  __shared__ __attribute__((aligned(16))) u16 P_lds[4 * 256];
  const int tid  = threadIdx.x;
  const int lane = tid & 63;
  const int wv   = tid >> 6;
  const int bs   = blockIdx.x;
  const int lg   = lane >> 4;
  const int lc   = lane & 15;
  const float scale = 0.125f;   // 1/sqrt(64)
  const f32x4 zf = {0.f, 0.f, 0.f, 0.f};

  for (int hh = 0; hh < 2; ++hh) {
    const int h = wv * 2 + hh;
    const size_t rowb = (size_t)(bs * 16 + lc) * NQKV;

    u16x8 aq0 = *(const u16x8*)(qkv + rowb + h * 64 + 0 * 32 + lg * 8);
    u16x8 aq1 = *(const u16x8*)(qkv + rowb + h * 64 + 1 * 32 + lg * 8);
    u16x8 bk0 = *(const u16x8*)(qkv + rowb + 512 + h * 64 + 0 * 32 + lg * 8);
    u16x8 bk1 = *(const u16x8*)(qkv + rowb + 512 + h * 64 + 1 * 32 + lg * 8);
    f32x4 s = mfma_bf16(aq0, bk0, zf);
    s = mfma_bf16(aq1, bk1, s);

#pragma unroll
    for (int r = 0; r < 4; ++r) {
      const int i = lg * 4 + r;
      float sv = s[r] * scale + pos_bias[h * 256 + i * 16 + lc];
      if (lc > i) sv = -1e30f;
      float m = sv;
#pragma unroll
      for (int off = 8; off >= 1; off >>= 1) m = fmaxf(m, __shfl_xor(m, off));
      float e = __expf(sv - m);
      float sm = e;
#pragma unroll
      for (int off = 8; off >= 1; off >>= 1) sm += __shfl_xor(sm, off);
      P_lds[wv * 256 + i * 16 + lc] = f2bf(e / sm);
    }
    asm volatile("s_waitcnt lgkmcnt(0)" ::: "memory");

    u16x8 ap = {0, 0, 0, 0, 0, 0, 0, 0};
    if (lane < 32) ap = *(const u16x8*)&P_lds[wv * 256 + lc * 16 + lg * 8];

#pragma unroll
    for (int nd = 0; nd < 4; ++nd) {
      u16x8 bv = {0, 0, 0, 0, 0, 0, 0, 0};
      if (lane < 32) {
#pragma unroll
        for (int jj = 0; jj < 8; ++jj) {
          int j = lg * 8 + jj;
          bv[jj] = qkv[(size_t)(bs * 16 + j) * NQKV + 1024 + h * 64 + nd * 16 + lc];
        }
      }
      f32x4 o = mfma_bf16(ap, bv, zf);
#pragma unroll
      for (int r = 0; r < 4; ++r) {
        const int i = lg * 4 + r;
        attn[(size_t)(bs * 16 + i) * 512 + h * 64 + nd * 16 + lc] = f2bf(o[r]);
      }
    }
  }
}

// ---------------- launch ----------------
extern "C" void kernel_launch(void* const* d_in, const int* in_sizes, int n_in,
                              void* d_out, int out_size, void* d_ws, size_t ws_size,
                              hipStream_t stream) {
  const float* x        = (const float*)d_in[0];
  const float* pos_bias = (const float*)d_in[1];
  const float* Wq       = (const float*)d_in[2];
  const float* Wk       = (const float*)d_in[3];
  const float* Wv       = (const float*)d_in[4];
  const float* Wo       = (const float*)d_in[5];
  const float* bo       = (const float*)d_in[6];
  float* out            = (float*)d_out;

  // ws layout (256 MiB budget):
  //   [0,   64 MiB): xb (bf16 x) -> reused as attnbuf after GEMM1
  //   [64, 256 MiB): qkv (bf16)  -> reused for Wo_t after attention
  // Wqkv_t (1.5 MiB) lives in d_out (fully overwritten by GEMM2 at the end).
  u16* xb      = (u16*)d_ws;                           // [65536][512]
  u16* qkv     = xb + (size_t)M_ROWS * 512;            // [65536][1536]
  u16* attnbuf = xb;                                   // [65536][512]
  u16* Wqkv_t  = (u16*)d_out;                          // [1536][512]
  u16* Wo_t    = qkv;                                  // [512][512]

  // 1) x -> bf16
  conv_x<<<dim3(M_ROWS * KDIM / (256 * 8)), dim3(256), 0, stream>>>(x, xb);

  // 2) Wq|Wk|Wv -> Wqkv_t[1536][512] bf16 (in d_out)
  convW_qkv<<<dim3(3072), dim3(256), 0, stream>>>(Wq, Wk, Wv, Wqkv_t);

  // 3) qkv = xb @ Wqkv  (M=65536, N=1536, K=512): 512x12 tiles = 6144 blocks
  gemm128<false><<<dim3(6144), dim3(256), 0, stream>>>(
      xb, Wqkv_t, (void*)qkv, (const float*)nullptr, NQKV, KDIM, 12);

  // 4) attention -> attnbuf (overwrites xb: dead)
  attn_kernel<<<dim3(4096), dim3(256), 0, stream>>>(qkv, pos_bias, attnbuf);

  // 5) Wo -> Wo_t (in dead qkv region)
  convWo<<<dim3(1024), dim3(256), 0, stream>>>(Wo, Wo_t);

  // 6) out = attnbuf @ Wo + bo  (M=65536, N=512, K=512): 512x4 tiles = 2048 blocks
  gemm128<true><<<dim3(2048), dim3(256), 0, stream>>>(
      attnbuf, Wo_t, (void*)out, bo, 512, KDIM, 4);
}

// Round 9
// 275.453 us; speedup vs baseline: 1.2310x; 1.1059x over previous
//
#include <hip/hip_runtime.h>

typedef unsigned short u16;
typedef __attribute__((ext_vector_type(8))) unsigned short u16x8;
typedef __attribute__((ext_vector_type(8))) __bf16 bf16x8;
typedef __attribute__((ext_vector_type(4))) float f32x4;

#define M_ROWS 65536   // b*s*f
#define NQKV   1536
#define KDIM   512

typedef __attribute__((address_space(1))) const void gconst_void;
typedef __attribute__((address_space(3))) void lds_void;

static __device__ __forceinline__ u16 f2bf(float f) {
  unsigned u = __builtin_bit_cast(unsigned, f);
  u += 0x7FFFu + ((u >> 16) & 1u);
  return (u16)(u >> 16);
}

static __device__ __forceinline__ f32x4 mfma_bf16(u16x8 a, u16x8 b, f32x4 c) {
  return __builtin_amdgcn_mfma_f32_16x16x32_bf16(
      __builtin_bit_cast(bf16x8, a), __builtin_bit_cast(bf16x8, b), c, 0, 0, 0);
}

// ---------------- fp32 -> bf16 convert (x) ----------------
__global__ void conv_x(const float* __restrict__ x, u16* __restrict__ xb) {
  const size_t t = (size_t)blockIdx.x * 256 + threadIdx.x;  // 8 elems/thread
  f32x4 a = *(const f32x4*)(x + t * 8);
  f32x4 b = *(const f32x4*)(x + t * 8 + 4);
  u16x8 w;
#pragma unroll
  for (int e = 0; e < 4; ++e) { w[e] = f2bf(a[e]); w[e + 4] = f2bf(b[e]); }
  *(u16x8*)(xb + t * 8) = w;
}

// ------ weight transpose+convert, LDS-tiled (coalesced both sides) ------
// Wt[n][k] = bf16(W[k][n]); n-space = q|k|v concatenated (1536).
__global__ void convW_qkv_t(const float* __restrict__ Wq, const float* __restrict__ Wk,
                            const float* __restrict__ Wv, u16* __restrict__ Wt) {
  __shared__ float tile[32][33];
  const int bn = blockIdx.x * 32;           // 0..1535 (output row block)
  const int bk = blockIdx.y * 32;           // 0..511  (output col block)
  const int tx = threadIdx.x & 31, ty = threadIdx.x >> 5;   // 32 x 8
  const float* W = (bn < 512) ? Wq : ((bn < 1024) ? Wk : Wv);
  const int coln = bn & 511;
#pragma unroll
  for (int r = 0; r < 32; r += 8)
    tile[ty + r][tx] = W[(size_t)(bk + ty + r) * 512 + coln + tx];
  __syncthreads();
#pragma unroll
  for (int r = 0; r < 32; r += 8)
    Wt[(size_t)(bn + ty + r) * 512 + bk + tx] = f2bf(tile[tx][ty + r]);
}

__global__ void convWo_t(const float* __restrict__ Wo, u16* __restrict__ Wt) {
  __shared__ float tile[32][33];
  const int bn = blockIdx.x * 32;
  const int bk = blockIdx.y * 32;
  const int tx = threadIdx.x & 31, ty = threadIdx.x >> 5;
#pragma unroll
  for (int r = 0; r < 32; r += 8)
    tile[ty + r][tx] = Wo[(size_t)(bk + ty + r) * 512 + bn + tx];
  __syncthreads();
#pragma unroll
  for (int r = 0; r < 32; r += 8)
    Wt[(size_t)(bn + ty + r) * 512 + bk + tx] = f2bf(tile[tx][ty + r]);
}

// ---------------- GEMM 256x256, BK=64, 8 waves (r3 verbatim) ----------
// Best-measured structure (135us GEMM1): 4 phases/K-tile, per-phase
// {2 gload_lds + ds_reads + barrier + lgkm0 + setprio'd 16 MFMA + barrier},
// 2-deep dbuf, boundary vmcnt(0).  T2 granule swizzle (conflicts=0),
// T1 XCD swizzle.  Counted-vmcnt / ring / occupancy variants all measured
// worse (r4-r8); do not touch without a within-probe A/B.
template <bool CF32>
__global__ __launch_bounds__(512, 2)
void gemm256(const u16* __restrict__ A, const u16* __restrict__ Bt,
             void* __restrict__ Cp, const float* __restrict__ bias,
             int N, int K, int n_tiles) {
  __shared__ __attribute__((aligned(16))) u16 smem[4][256 * 64];  // A0,A1,B0,B1

  const int tid  = threadIdx.x;
  const int lane = tid & 63;
  const int wid  = tid >> 6;        // 0..7
  const int wm   = wid >> 2;        // 0..1  (M half)
  const int wn   = wid & 3;         // 0..3  (N quarter)
  const int lg   = lane >> 4;       // 0..3
  const int lc   = lane & 15;
  const int srow = lane >> 3;       // 0..7  staging row within 8-row slab
  const int sg   = (lane & 7) ^ srow;  // pre-swizzled source granule

  // T1: XCD-aware swizzle (grid % 8 == 0 for both GEMMs)
  const int nwg  = gridDim.x;
  const int cpx  = nwg >> 3;
  const int flat = blockIdx.x;
  const int swz  = (flat & 7) * cpx + (flat >> 3);
  const int mt   = swz / n_tiles;
  const int nt   = swz % n_tiles;
  const int row0 = mt * 256, col0 = nt * 256;

  // stage phase ph of tile kt into buffer b: 2 x global_load_lds (1KB each)
  auto stagePh = [&](int ph, int b, int kt) {
    const int k0 = kt * 64;
#pragma unroll
    for (int cc = 0; cc < 2; ++cc) {
      if (ph < 2) {
        const int c2 = ph * 2 + cc;                 // A slab 0..3
        const int rl = wid * 32 + c2 * 8;           // wave-uniform LDS row base
        const u16* src = A + (size_t)(row0 + rl + srow) * K + k0 + sg * 8;
        __builtin_amdgcn_global_load_lds((gconst_void*)src,
                                         (lds_void*)&smem[b][rl * 64], 16, 0, 0);
      } else {
        const int c2 = (ph - 2) * 2 + cc;           // B slab 0..3
        const int rl = wid * 32 + c2 * 8;
        const u16* src = Bt + (size_t)(col0 + rl + srow) * K + k0 + sg * 8;
        __builtin_amdgcn_global_load_lds((gconst_void*)src,
                                         (lds_void*)&smem[2 + b][rl * 64], 16, 0, 0);
      }
    }
  };

  f32x4 acc[8][4];
#pragma unroll
  for (int mi = 0; mi < 8; ++mi)
#pragma unroll
    for (int ni = 0; ni < 4; ++ni) acc[mi][ni] = (f32x4){0.f, 0.f, 0.f, 0.f};

  const int nkt = K >> 6;   // 8

  // prologue: stage tile 0 into buf 0
#pragma unroll
  for (int ph = 0; ph < 4; ++ph) stagePh(ph, 0, 0);
  asm volatile("s_waitcnt vmcnt(0)" ::: "memory");
  __builtin_amdgcn_s_barrier();

  for (int t = 0; t < nkt; ++t) {
    const int  c   = t & 1;
    const bool pre = (t + 1) < nkt;
    const u16* Asb = &smem[c][0];
    const u16* Bsb = &smem[2 + c][0];
    u16x8 af[4], bfr[4];

#pragma unroll
    for (int ph = 0; ph < 4; ++ph) {
      const int ks = ph >> 1;   // k-slice 0/1
      const int mh = ph & 1;    // M-half of wave tile
      const int gsw = ((ks * 4 + lg) ^ (lc & 7)) << 3;  // swizzled granule (elems)
      if (mh == 0) {
#pragma unroll
        for (int ni = 0; ni < 4; ++ni)
          bfr[ni] = *(const u16x8*)&Bsb[(wn * 64 + ni * 16 + lc) * 64 + gsw];
      }
#pragma unroll
      for (int i = 0; i < 4; ++i)
        af[i] = *(const u16x8*)&Asb[(wm * 128 + (mh * 4 + i) * 16 + lc) * 64 + gsw];
      if (pre) stagePh(ph, c ^ 1, t + 1);

      __builtin_amdgcn_s_barrier();
      asm volatile("s_waitcnt lgkmcnt(0)" ::: "memory");
      __builtin_amdgcn_sched_barrier(0);
      __builtin_amdgcn_s_setprio(1);
#pragma unroll
      for (int i = 0; i < 4; ++i)
#pragma unroll
        for (int ni = 0; ni < 4; ++ni)
          acc[mh * 4 + i][ni] = mfma_bf16(af[i], bfr[ni], acc[mh * 4 + i][ni]);
      __builtin_amdgcn_s_setprio(0);
      __builtin_amdgcn_sched_barrier(0);
      if (ph < 3) __builtin_amdgcn_s_barrier();
    }
    // tile boundary: tile t+1's loads (issued during phases above) must land
    asm volatile("s_waitcnt vmcnt(0)" ::: "memory");
    __builtin_amdgcn_s_barrier();
  }

  // epilogue
  const int gmb = row0 + wm * 128;
  const int gnb = col0 + wn * 64;
#pragma unroll
  for (int mi = 0; mi < 8; ++mi)
#pragma unroll
    for (int ni = 0; ni < 4; ++ni) {
      const int gm = gmb + mi * 16 + lg * 4;
      const int gn = gnb + ni * 16 + lc;
      f32x4 v = acc[mi][ni];
      if constexpr (CF32) {
        float* C = (float*)Cp;
        float bv = bias[gn];
#pragma unroll
        for (int r = 0; r < 4; ++r) C[(size_t)(gm + r) * N + gn] = v[r] + bv;
      } else {
        u16* C = (u16*)Cp;
#pragma unroll
        for (int r = 0; r < 4; ++r) C[(size_t)(gm + r) * N + gn] = f2bf(v[r]);
      }
    }
}

// ---------------- attention over frames (f=16) ----------------
__global__ __launch_bounds__(256, 4)
void attn_kernel(const u16* __restrict__ qkv, const float* __restrict__ pos_bias,
                 u16* __restrict__ attn) {
  __shared__ __attribute__((aligned(16))) u16 P_lds[4 * 256];
  const int tid  = threadIdx.x;
  const int lane = tid & 63;
  const int wv   = tid >> 6;
  const int bs   = blockIdx.x;
  const int lg   = lane >> 4;
  const int lc   = lane & 15;
  const float scale = 0.125f;   // 1/sqrt(64)
  const f32x4 zf = {0.f, 0.f, 0.f, 0.f};

  for (int hh = 0; hh < 2; ++hh) {
    const int h = wv * 2 + hh;
    const size_t rowb = (size_t)(bs * 16 + lc) * NQKV;

    u16x8 aq0 = *(const u16x8*)(qkv + rowb + h * 64 + 0 * 32 + lg * 8);
    u16x8 aq1 = *(const u16x8*)(qkv + rowb + h * 64 + 1 * 32 + lg * 8);
    u16x8 bk0 = *(const u16x8*)(qkv + rowb + 512 + h * 64 + 0 * 32 + lg * 8);
    u16x8 bk1 = *(const u16x8*)(qkv + rowb + 512 + h * 64 + 1 * 32 + lg * 8);
    f32x4 s = mfma_bf16(aq0, bk0, zf);
    s = mfma_bf16(aq1, bk1, s);

#pragma unroll
    for (int r = 0; r < 4; ++r) {
      const int i = lg * 4 + r;
      float sv = s[r] * scale + pos_bias[h * 256 + i * 16 + lc];
      if (lc > i) sv = -1e30f;
      float m = sv;
#pragma unroll
      for (int off = 8; off >= 1; off >>= 1) m = fmaxf(m, __shfl_xor(m, off));
      float e = __expf(sv - m);
      float sm = e;
#pragma unroll
      for (int off = 8; off >= 1; off >>= 1) sm += __shfl_xor(sm, off);
      P_lds[wv * 256 + i * 16 + lc] = f2bf(e / sm);
    }
    asm volatile("s_waitcnt lgkmcnt(0)" ::: "memory");

    u16x8 ap = {0, 0, 0, 0, 0, 0, 0, 0};
    if (lane < 32) ap = *(const u16x8*)&P_lds[wv * 256 + lc * 16 + lg * 8];

#pragma unroll
    for (int nd = 0; nd < 4; ++nd) {
      u16x8 bv = {0, 0, 0, 0, 0, 0, 0, 0};
      if (lane < 32) {
#pragma unroll
        for (int jj = 0; jj < 8; ++jj) {
          int j = lg * 8 + jj;
          bv[jj] = qkv[(size_t)(bs * 16 + j) * NQKV + 1024 + h * 64 + nd * 16 + lc];
        }
      }
      f32x4 o = mfma_bf16(ap, bv, zf);
#pragma unroll
      for (int r = 0; r < 4; ++r) {
        const int i = lg * 4 + r;
        attn[(size_t)(bs * 16 + i) * 512 + h * 64 + nd * 16 + lc] = f2bf(o[r]);
      }
    }
  }
}

// ---------------- launch ----------------
extern "C" void kernel_launch(void* const* d_in, const int* in_sizes, int n_in,
                              void* d_out, int out_size, void* d_ws, size_t ws_size,
                              hipStream_t stream) {
  const float* x        = (const float*)d_in[0];
  const float* pos_bias = (const float*)d_in[1];
  const float* Wq       = (const float*)d_in[2];
  const float* Wk       = (const float*)d_in[3];
  const float* Wv       = (const float*)d_in[4];
  const float* Wo       = (const float*)d_in[5];
  const float* bo       = (const float*)d_in[6];
  float* out            = (float*)d_out;

  // ws layout (256 MiB budget):
  //   [0,   64 MiB): xb (bf16 x) -> reused as attnbuf after GEMM1
  //   [64, 256 MiB): qkv (bf16)  -> reused for Wo_t after attention
  // Wqkv_t (1.5 MiB) lives in d_out (fully overwritten by GEMM2 at the end).
  u16* xb      = (u16*)d_ws;                           // [65536][512]
  u16* qkv     = xb + (size_t)M_ROWS * 512;            // [65536][1536]
  u16* attnbuf = xb;                                   // [65536][512]
  u16* Wqkv_t  = (u16*)d_out;                          // [1536][512]
  u16* Wo_t    = qkv;                                  // [512][512]

  // 1) x -> bf16
  conv_x<<<dim3(M_ROWS * KDIM / (256 * 8)), dim3(256), 0, stream>>>(x, xb);

  // 2) Wq|Wk|Wv -> Wqkv_t[1536][512] bf16 (in d_out), coalesced transpose
  convW_qkv_t<<<dim3(48, 16), dim3(256), 0, stream>>>(Wq, Wk, Wv, Wqkv_t);

  // 3) qkv = xb @ Wqkv  (M=65536, N=1536, K=512): 256x6 tiles = 1536 blocks
  gemm256<false><<<dim3(1536), dim3(512), 0, stream>>>(
      xb, Wqkv_t, (void*)qkv, (const float*)nullptr, NQKV, KDIM, 6);

  // 4) attention -> attnbuf (overwrites xb: dead)
  attn_kernel<<<dim3(4096), dim3(256), 0, stream>>>(qkv, pos_bias, attnbuf);

  // 5) Wo -> Wo_t (in dead qkv region), coalesced transpose
  convWo_t<<<dim3(16, 16), dim3(256), 0, stream>>>(Wo, Wo_t);

  // 6) out = attnbuf @ Wo + bo  (M=65536, N=512, K=512): 256x2 tiles = 512 blocks
  gemm256<true><<<dim3(512), dim3(512), 0, stream>>>(
      attnbuf, Wo_t, (void*)out, bo, 512, KDIM, 2);
}

// Round 10
// 225.097 us; speedup vs baseline: 1.5064x; 1.2237x over previous
//
#include <hip/hip_runtime.h>

typedef unsigned short u16;
typedef __attribute__((ext_vector_type(8))) unsigned short u16x8;
typedef __attribute__((ext_vector_type(8))) __bf16 bf16x8;
typedef __attribute__((ext_vector_type(4))) float f32x4;

#define M_ROWS 65536   // b*s*f
#define NQKV   1536
#define KDIM   512

typedef __attribute__((address_space(1))) const void gconst_void;
typedef __attribute__((address_space(3))) void lds_void;

static __device__ __forceinline__ u16 f2bf(float f) {
  unsigned u = __builtin_bit_cast(unsigned, f);
  u += 0x7FFFu + ((u >> 16) & 1u);
  return (u16)(u >> 16);
}

static __device__ __forceinline__ f32x4 mfma_bf16(u16x8 a, u16x8 b, f32x4 c) {
  return __builtin_amdgcn_mfma_f32_16x16x32_bf16(
      __builtin_bit_cast(bf16x8, a), __builtin_bit_cast(bf16x8, b), c, 0, 0, 0);
}

// ---------------- fp32 -> bf16 convert (x) ----------------
__global__ void conv_x(const float* __restrict__ x, u16* __restrict__ xb) {
  const size_t t = (size_t)blockIdx.x * 256 + threadIdx.x;  // 8 elems/thread
  f32x4 a = *(const f32x4*)(x + t * 8);
  f32x4 b = *(const f32x4*)(x + t * 8 + 4);
  u16x8 w;
#pragma unroll
  for (int e = 0; e < 4; ++e) { w[e] = f2bf(a[e]); w[e + 4] = f2bf(b[e]); }
  *(u16x8*)(xb + t * 8) = w;
}

// ------ weight transpose+convert, LDS-tiled (coalesced both sides) ------
__global__ void convW_qkv_t(const float* __restrict__ Wq, const float* __restrict__ Wk,
                            const float* __restrict__ Wv, u16* __restrict__ Wt) {
  __shared__ float tile[32][33];
  const int bn = blockIdx.x * 32;
  const int bk = blockIdx.y * 32;
  const int tx = threadIdx.x & 31, ty = threadIdx.x >> 5;
  const float* W = (bn < 512) ? Wq : ((bn < 1024) ? Wk : Wv);
  const int coln = bn & 511;
#pragma unroll
  for (int r = 0; r < 32; r += 8)
    tile[ty + r][tx] = W[(size_t)(bk + ty + r) * 512 + coln + tx];
  __syncthreads();
#pragma unroll
  for (int r = 0; r < 32; r += 8)
    Wt[(size_t)(bn + ty + r) * 512 + bk + tx] = f2bf(tile[tx][ty + r]);
}

__global__ void convWo_t(const float* __restrict__ Wo, u16* __restrict__ Wt) {
  __shared__ float tile[32][33];
  const int bn = blockIdx.x * 32;
  const int bk = blockIdx.y * 32;
  const int tx = threadIdx.x & 31, ty = threadIdx.x >> 5;
#pragma unroll
  for (int r = 0; r < 32; r += 8)
    tile[ty + r][tx] = Wo[(size_t)(bk + ty + r) * 512 + bn + tx];
  __syncthreads();
#pragma unroll
  for (int r = 0; r < 32; r += 8)
    Wt[(size_t)(bn + ty + r) * 512 + bk + tx] = f2bf(tile[tx][ty + r]);
}

// -------- FUSED: qkv projection (one head) + attention -> attnbuf --------
// Block = 256 A-rows (16 tokens) x 192 weight cols (head h's q|k|v).
// K-loop = r3's proven 4-phase schedule (same swizzle/barriers); waves
// mapped 4M x 2N (per-wave 64 rows x 96 cols, acc 4x6).  Epilogue: acc ->
// bf16 -> LDS qkvT[256][200], __syncthreads, then the verified attention
// math reading LDS, writing attnbuf rows directly.  Kills the 192 MiB qkv
// write + 192 MiB read and the separate attn dispatch.
__global__ __launch_bounds__(512, 2)
void gemm_qkv_attn(const u16* __restrict__ A, const u16* __restrict__ Wt,
                   const float* __restrict__ pos_bias, u16* __restrict__ attnbuf) {
  // LDS plan (u16 elems, 57344 total = 112 KiB):
  //   K-loop:  Ab [2][16384] at 0;  Bb [2][12288] at 32768
  //   post:    qkvT [256][200] at 0 (51200); Pl [8][2][256] at 51200 (4096)
  __shared__ __attribute__((aligned(16))) u16 smem[57344];
  u16* Ab   = smem;
  u16* Bb   = smem + 32768;
  u16* qkvT = smem;
  u16* Pl   = smem + 51200;

  const int tid  = threadIdx.x;
  const int lane = tid & 63;
  const int wid  = tid >> 6;        // 0..7
  const int wm   = wid >> 1;        // 0..3  (M quarter: 64 rows)
  const int wn   = wid & 1;         // 0..1  (N half: 96 cols)
  const int lg   = lane >> 4;       // 0..3
  const int lc   = lane & 15;
  const int srow = lane >> 3;       // 0..7
  const int sg   = (lane & 7) ^ srow;  // pre-swizzled source granule

  // XCD swizzle; grid = 2048 (%8==0).  h fastest -> A-panel L2 reuse x8.
  const int nwg  = gridDim.x;
  const int cpx  = nwg >> 3;
  const int flat = blockIdx.x;
  const int swz  = (flat & 7) * cpx + (flat >> 3);
  const int mt   = swz >> 3;
  const int h    = swz & 7;
  const int row0 = mt * 256;

  auto stagePh = [&](int ph, int b, int kt) {
    const int k0 = kt * 64;
    if (ph < 2) {            // A: 4 loads over ph0/ph1 (32 rows/wave)
#pragma unroll
      for (int cc = 0; cc < 2; ++cc) {
        const int rl = wid * 32 + (ph * 2 + cc) * 8;
        const u16* src = A + (size_t)(row0 + rl + srow) * KDIM + k0 + sg * 8;
        __builtin_amdgcn_global_load_lds((gconst_void*)src,
                                         (lds_void*)&Ab[b * 16384 + rl * 64], 16, 0, 0);
      }
    } else {                 // B: 3 loads over ph2(2)/ph3(1) (24 rows/wave)
      const int nj = (ph == 2) ? 2 : 1;
#pragma unroll
      for (int jj = 0; jj < 2; ++jj) {
        if (jj < nj) {
          const int j  = (ph == 2) ? jj : 2;
          const int rl = wid * 24 + j * 8;
          const int n  = rl + srow;                       // 0..191
          const int grow = (n >> 6) * 512 + h * 64 + (n & 63);
          const u16* src = Wt + (size_t)grow * KDIM + k0 + sg * 8;
          __builtin_amdgcn_global_load_lds((gconst_void*)src,
                                           (lds_void*)&Bb[b * 12288 + rl * 64], 16, 0, 0);
        }
      }
    }
  };

  f32x4 acc[4][6];
#pragma unroll
  for (int mi = 0; mi < 4; ++mi)
#pragma unroll
    for (int ni = 0; ni < 6; ++ni) acc[mi][ni] = (f32x4){0.f, 0.f, 0.f, 0.f};

  // prologue: stage tile 0
#pragma unroll
  for (int ph = 0; ph < 4; ++ph) stagePh(ph, 0, 0);
  asm volatile("s_waitcnt vmcnt(0)" ::: "memory");
  __builtin_amdgcn_s_barrier();

  for (int t = 0; t < 8; ++t) {
    const int  c   = t & 1;
    const bool pre = (t + 1) < 8;
    const u16* Asb = &Ab[c * 16384];
    const u16* Bsb = &Bb[c * 12288];
    u16x8 af[2], bfr[6];

#pragma unroll
    for (int ph = 0; ph < 4; ++ph) {
      const int ks = ph >> 1;
      const int mh = ph & 1;
      const int gsw = ((ks * 4 + lg) ^ (lc & 7)) << 3;
      if (mh == 0) {
#pragma unroll
        for (int ni = 0; ni < 6; ++ni)
          bfr[ni] = *(const u16x8*)&Bsb[(wn * 96 + ni * 16 + lc) * 64 + gsw];
      }
#pragma unroll
      for (int i = 0; i < 2; ++i)
        af[i] = *(const u16x8*)&Asb[(wm * 64 + (mh * 2 + i) * 16 + lc) * 64 + gsw];
      if (pre) stagePh(ph, c ^ 1, t + 1);

      __builtin_amdgcn_s_barrier();
      asm volatile("s_waitcnt lgkmcnt(0)" ::: "memory");
      __builtin_amdgcn_sched_barrier(0);
      __builtin_amdgcn_s_setprio(1);
#pragma unroll
      for (int i = 0; i < 2; ++i)
#pragma unroll
        for (int ni = 0; ni < 6; ++ni)
          acc[mh * 2 + i][ni] = mfma_bf16(af[i], bfr[ni], acc[mh * 2 + i][ni]);
      __builtin_amdgcn_s_setprio(0);
      __builtin_amdgcn_sched_barrier(0);
      if (ph < 3) __builtin_amdgcn_s_barrier();
    }
    asm volatile("s_waitcnt vmcnt(0)" ::: "memory");
    __builtin_amdgcn_s_barrier();
  }

  // ---- epilogue: acc -> bf16 -> qkvT[256][200] (aliases K-loop LDS) ----
#pragma unroll
  for (int mi = 0; mi < 4; ++mi)
#pragma unroll
    for (int ni = 0; ni < 6; ++ni) {
      const int col = wn * 96 + ni * 16 + lc;
      const int rb  = wm * 64 + mi * 16 + lg * 4;
#pragma unroll
      for (int r = 0; r < 4; ++r)
        qkvT[(rb + r) * 200 + col] = f2bf(acc[mi][ni][r]);
    }
  __syncthreads();

  // ---- attention (verified math, LDS-resident): wave -> 2 tokens ----
  const float scale = 0.125f;
  const f32x4 zf = {0.f, 0.f, 0.f, 0.f};
#pragma unroll
  for (int tt = 0; tt < 2; ++tt) {
    const int tok = wid * 2 + tt;
    const int rb  = tok * 16;
    const int qb  = (rb + lc) * 200;

    u16x8 aq0 = *(const u16x8*)&qkvT[qb + 0  + lg * 8];
    u16x8 aq1 = *(const u16x8*)&qkvT[qb + 32 + lg * 8];
    u16x8 bk0 = *(const u16x8*)&qkvT[qb + 64 + lg * 8];
    u16x8 bk1 = *(const u16x8*)&qkvT[qb + 96 + lg * 8];
    f32x4 s = mfma_bf16(aq0, bk0, zf);
    s = mfma_bf16(aq1, bk1, s);

    const int pb = wid * 512 + tt * 256;
#pragma unroll
    for (int r = 0; r < 4; ++r) {
      const int i = lg * 4 + r;
      float sv = s[r] * scale + pos_bias[h * 256 + i * 16 + lc];
      if (lc > i) sv = -1e30f;
      float m = sv;
#pragma unroll
      for (int off = 8; off >= 1; off >>= 1) m = fmaxf(m, __shfl_xor(m, off));
      float e = __expf(sv - m);
      float sm = e;
#pragma unroll
      for (int off = 8; off >= 1; off >>= 1) sm += __shfl_xor(sm, off);
      Pl[pb + i * 16 + lc] = f2bf(e / sm);
    }
    asm volatile("s_waitcnt lgkmcnt(0)" ::: "memory");

    u16x8 ap = {0, 0, 0, 0, 0, 0, 0, 0};
    if (lane < 32) ap = *(const u16x8*)&Pl[pb + lc * 16 + lg * 8];

#pragma unroll
    for (int nd = 0; nd < 4; ++nd) {
      u16x8 bv = {0, 0, 0, 0, 0, 0, 0, 0};
      if (lane < 32) {
#pragma unroll
        for (int jj = 0; jj < 8; ++jj) {
          const int j = lg * 8 + jj;
          bv[jj] = qkvT[(rb + j) * 200 + 128 + nd * 16 + lc];
        }
      }
      f32x4 o = mfma_bf16(ap, bv, zf);
#pragma unroll
      for (int r = 0; r < 4; ++r) {
        const int i = lg * 4 + r;
        attnbuf[(size_t)(row0 + rb + i) * 512 + h * 64 + nd * 16 + lc] = f2bf(o[r]);
      }
    }
  }
}

// ---------------- GEMM 256x256, BK=64, 8 waves (r3 verbatim) ----------
template <bool CF32>
__global__ __launch_bounds__(512, 2)
void gemm256(const u16* __restrict__ A, const u16* __restrict__ Bt,
             void* __restrict__ Cp, const float* __restrict__ bias,
             int N, int K, int n_tiles) {
  __shared__ __attribute__((aligned(16))) u16 smem[4][256 * 64];

  const int tid  = threadIdx.x;
  const int lane = tid & 63;
  const int wid  = tid >> 6;
  const int wm   = wid >> 2;
  const int wn   = wid & 3;
  const int lg   = lane >> 4;
  const int lc   = lane & 15;
  const int srow = lane >> 3;
  const int sg   = (lane & 7) ^ srow;

  const int nwg  = gridDim.x;
  const int cpx  = nwg >> 3;
  const int flat = blockIdx.x;
  const int swz  = (flat & 7) * cpx + (flat >> 3);
  const int mt   = swz / n_tiles;
  const int nt   = swz % n_tiles;
  const int row0 = mt * 256, col0 = nt * 256;

  auto stagePh = [&](int ph, int b, int kt) {
    const int k0 = kt * 64;
#pragma unroll
    for (int cc = 0; cc < 2; ++cc) {
      if (ph < 2) {
        const int c2 = ph * 2 + cc;
        const int rl = wid * 32 + c2 * 8;
        const u16* src = A + (size_t)(row0 + rl + srow) * K + k0 + sg * 8;
        __builtin_amdgcn_global_load_lds((gconst_void*)src,
                                         (lds_void*)&smem[b][rl * 64], 16, 0, 0);
      } else {
        const int c2 = (ph - 2) * 2 + cc;
        const int rl = wid * 32 + c2 * 8;
        const u16* src = Bt + (size_t)(col0 + rl + srow) * K + k0 + sg * 8;
        __builtin_amdgcn_global_load_lds((gconst_void*)src,
                                         (lds_void*)&smem[2 + b][rl * 64], 16, 0, 0);
      }
    }
  };

  f32x4 acc[8][4];
#pragma unroll
  for (int mi = 0; mi < 8; ++mi)
#pragma unroll
    for (int ni = 0; ni < 4; ++ni) acc[mi][ni] = (f32x4){0.f, 0.f, 0.f, 0.f};

  const int nkt = K >> 6;

#pragma unroll
  for (int ph = 0; ph < 4; ++ph) stagePh(ph, 0, 0);
  asm volatile("s_waitcnt vmcnt(0)" ::: "memory");
  __builtin_amdgcn_s_barrier();

  for (int t = 0; t < nkt; ++t) {
    const int  c   = t & 1;
    const bool pre = (t + 1) < nkt;
    const u16* Asb = &smem[c][0];
    const u16* Bsb = &smem[2 + c][0];
    u16x8 af[4], bfr[4];

#pragma unroll
    for (int ph = 0; ph < 4; ++ph) {
      const int ks = ph >> 1;
      const int mh = ph & 1;
      const int gsw = ((ks * 4 + lg) ^ (lc & 7)) << 3;
      if (mh == 0) {
#pragma unroll
        for (int ni = 0; ni < 4; ++ni)
          bfr[ni] = *(const u16x8*)&Bsb[(wn * 64 + ni * 16 + lc) * 64 + gsw];
      }
#pragma unroll
      for (int i = 0; i < 4; ++i)
        af[i] = *(const u16x8*)&Asb[(wm * 128 + (mh * 4 + i) * 16 + lc) * 64 + gsw];
      if (pre) stagePh(ph, c ^ 1, t + 1);

      __builtin_amdgcn_s_barrier();
      asm volatile("s_waitcnt lgkmcnt(0)" ::: "memory");
      __builtin_amdgcn_sched_barrier(0);
      __builtin_amdgcn_s_setprio(1);
#pragma unroll
      for (int i = 0; i < 4; ++i)
#pragma unroll
        for (int ni = 0; ni < 4; ++ni)
          acc[mh * 4 + i][ni] = mfma_bf16(af[i], bfr[ni], acc[mh * 4 + i][ni]);
      __builtin_amdgcn_s_setprio(0);
      __builtin_amdgcn_sched_barrier(0);
      if (ph < 3) __builtin_amdgcn_s_barrier();
    }
    asm volatile("s_waitcnt vmcnt(0)" ::: "memory");
    __builtin_amdgcn_s_barrier();
  }

  const int gmb = row0 + wm * 128;
  const int gnb = col0 + wn * 64;
#pragma unroll
  for (int mi = 0; mi < 8; ++mi)
#pragma unroll
    for (int ni = 0; ni < 4; ++ni) {
      const int gm = gmb + mi * 16 + lg * 4;
      const int gn = gnb + ni * 16 + lc;
      f32x4 v = acc[mi][ni];
      if constexpr (CF32) {
        float* C = (float*)Cp;
        float bv = bias[gn];
#pragma unroll
        for (int r = 0; r < 4; ++r) C[(size_t)(gm + r) * N + gn] = v[r] + bv;
      } else {
        u16* C = (u16*)Cp;
#pragma unroll
        for (int r = 0; r < 4; ++r) C[(size_t)(gm + r) * N + gn] = f2bf(v[r]);
      }
    }
}

// ---------------- launch ----------------
extern "C" void kernel_launch(void* const* d_in, const int* in_sizes, int n_in,
                              void* d_out, int out_size, void* d_ws, size_t ws_size,
                              hipStream_t stream) {
  const float* x        = (const float*)d_in[0];
  const float* pos_bias = (const float*)d_in[1];
  const float* Wq       = (const float*)d_in[2];
  const float* Wk       = (const float*)d_in[3];
  const float* Wv       = (const float*)d_in[4];
  const float* Wo       = (const float*)d_in[5];
  const float* bo       = (const float*)d_in[6];
  float* out            = (float*)d_out;

  // ws layout (256 MiB):
  //   [0,    64 MiB): xb (bf16 x)          -- read by fused kernel
  //   [64,  128 MiB): attnbuf (bf16)       -- written by fused, read by GEMM2
  //   [128, 129 MiB): Wo_t
  // Wqkv_t (1.5 MiB) in d_out (dead until GEMM2 overwrites all of d_out).
  u16* xb      = (u16*)d_ws;                           // [65536][512]
  u16* attnbuf = xb + (size_t)M_ROWS * 512;            // [65536][512]
  u16* Wo_t    = attnbuf + (size_t)M_ROWS * 512;       // [512][512]
  u16* Wqkv_t  = (u16*)d_out;                          // [1536][512]

  // 1) x -> bf16
  conv_x<<<dim3(M_ROWS * KDIM / (256 * 8)), dim3(256), 0, stream>>>(x, xb);

  // 2) Wq|Wk|Wv -> Wqkv_t (coalesced transpose, into d_out)
  convW_qkv_t<<<dim3(48, 16), dim3(256), 0, stream>>>(Wq, Wk, Wv, Wqkv_t);

  // 3) fused qkv-projection + attention -> attnbuf (2048 = 256 mt x 8 heads)
  gemm_qkv_attn<<<dim3(2048), dim3(512), 0, stream>>>(xb, Wqkv_t, pos_bias, attnbuf);

  // 4) Wo -> Wo_t (coalesced transpose)
  convWo_t<<<dim3(16, 16), dim3(256), 0, stream>>>(Wo, Wo_t);

  // 5) out = attnbuf @ Wo + bo  (M=65536, N=512, K=512): 512 blocks
  gemm256<true><<<dim3(512), dim3(512), 0, stream>>>(
      attnbuf, Wo_t, (void*)out, bo, 512, KDIM, 2);
}

// Round 11
// 224.252 us; speedup vs baseline: 1.5120x; 1.0038x over previous
//
#include <hip/hip_runtime.h>

typedef unsigned short u16;
typedef __attribute__((ext_vector_type(8))) unsigned short u16x8;
typedef __attribute__((ext_vector_type(8))) __bf16 bf16x8;
typedef __attribute__((ext_vector_type(4))) float f32x4;

#define M_ROWS 65536   // b*s*f
#define KDIM   512
#define NKT    8       // KDIM / 64

typedef __attribute__((address_space(1))) const void gconst_void;
typedef __attribute__((address_space(3))) void lds_void;

static __device__ __forceinline__ u16 f2bf(float f) {
  unsigned u = __builtin_bit_cast(unsigned, f);
  u += 0x7FFFu + ((u >> 16) & 1u);
  return (u16)(u >> 16);
}

static __device__ __forceinline__ f32x4 mfma_bf16(u16x8 a, u16x8 b, f32x4 c) {
  return __builtin_amdgcn_mfma_f32_16x16x32_bf16(
      __builtin_bit_cast(bf16x8, a), __builtin_bit_cast(bf16x8, b), c, 0, 0, 0);
}

// ---------------- fp32 -> bf16 convert (x) ----------------
__global__ void conv_x(const float* __restrict__ x, u16* __restrict__ xb) {
  const size_t t = (size_t)blockIdx.x * 256 + threadIdx.x;
  f32x4 a = *(const f32x4*)(x + t * 8);
  f32x4 b = *(const f32x4*)(x + t * 8 + 4);
  u16x8 w;
#pragma unroll
  for (int e = 0; e < 4; ++e) { w[e] = f2bf(a[e]); w[e + 4] = f2bf(b[e]); }
  *(u16x8*)(xb + t * 8) = w;
}

// ------ weight transpose+convert, LDS-tiled ------
__global__ void convW_qkv_t(const float* __restrict__ Wq, const float* __restrict__ Wk,
                            const float* __restrict__ Wv, u16* __restrict__ Wt) {
  __shared__ float tile[32][33];
  const int bn = blockIdx.x * 32;
  const int bk = blockIdx.y * 32;
  const int tx = threadIdx.x & 31, ty = threadIdx.x >> 5;
  const float* W = (bn < 512) ? Wq : ((bn < 1024) ? Wk : Wv);
  const int coln = bn & 511;
#pragma unroll
  for (int r = 0; r < 32; r += 8)
    tile[ty + r][tx] = W[(size_t)(bk + ty + r) * 512 + coln + tx];
  __syncthreads();
#pragma unroll
  for (int r = 0; r < 32; r += 8)
    Wt[(size_t)(bn + ty + r) * 512 + bk + tx] = f2bf(tile[tx][ty + r]);
}

__global__ void convWo_t(const float* __restrict__ Wo, u16* __restrict__ Wt) {
  __shared__ float tile[32][33];
  const int bn = blockIdx.x * 32;
  const int bk = blockIdx.y * 32;
  const int tx = threadIdx.x & 31, ty = threadIdx.x >> 5;
#pragma unroll
  for (int r = 0; r < 32; r += 8)
    tile[ty + r][tx] = Wo[(size_t)(bk + ty + r) * 512 + bn + tx];
  __syncthreads();
#pragma unroll
  for (int r = 0; r < 32; r += 8)
    Wt[(size_t)(bn + ty + r) * 512 + bk + tx] = f2bf(tile[tx][ty + r]);
}

// -------- FUSED qkv projection (one head) + attention, counted-vmcnt ------
// r10 structure with the drain-0 boundary replaced by an exact vmcnt ledger:
// stage units = one gload_lds call (64 rows x 64 k, 1KB/wave).  A ring-of-3
// (A(t+2) prefetch), B ring-of-2 (B(t+1)).  Issue order per tile t:
// ph0:B0,B1(t+1) ph1:B2(t+1),A0(t+2) ph2:A1,A2(t+2) ph3:A3(t+2).
// Tile-top in-flight = A(t)4 + B(t)3 + A(t+1)4 = 11 -> s_waitcnt vmcnt(4)
// retires exactly tile t's units; windows 4-8 phases >> HBM latency.
__global__ __launch_bounds__(512, 2)
void gemm_qkv_attn(const u16* __restrict__ A, const u16* __restrict__ Wt,
                   const float* __restrict__ pos_bias, u16* __restrict__ attnbuf) {
  // smem u16[73728] = 144 KiB: Ab[3][16384] | Bb[2][12288]
  // post-loop alias: qkvT[256][200] at 0, Pl[4096] at 51200
  __shared__ __attribute__((aligned(16))) u16 smem[73728];
  u16* Ab   = smem;
  u16* Bb   = smem + 49152;
  u16* qkvT = smem;
  u16* Pl   = smem + 51200;

  const int tid  = threadIdx.x;
  const int lane = tid & 63;
  const int wid  = tid >> 6;        // 0..7
  const int wm   = wid >> 1;        // 0..3 (64-row band)
  const int wn   = wid & 1;         // 0..1 (96-col band)
  const int lg   = lane >> 4;
  const int lc   = lane & 15;
  const int srow = lane >> 3;       // 0..7
  const int sg   = (lane & 7) ^ srow;

  const int nwg  = gridDim.x;
  const int cpx  = nwg >> 3;
  const int flat = blockIdx.x;
  const int swz  = (flat & 7) * cpx + (flat >> 3);
  const int mt   = swz >> 3;
  const int h    = swz & 7;
  const int row0 = mt * 256;

  auto stageA = [&](int buf, int unit, int kt) {
    const int rl = unit * 64 + wid * 8;
    const u16* src = A + (size_t)(row0 + rl + srow) * KDIM + kt * 64 + sg * 8;
    __builtin_amdgcn_global_load_lds((gconst_void*)src,
                                     (lds_void*)&Ab[buf * 16384 + rl * 64], 16, 0, 0);
  };
  auto stageB = [&](int buf, int unit, int kt) {
    const int rl = unit * 64 + wid * 8;
    const int grow = unit * 512 + h * 64 + wid * 8 + srow;
    const u16* src = Wt + (size_t)grow * KDIM + kt * 64 + sg * 8;
    __builtin_amdgcn_global_load_lds((gconst_void*)src,
                                     (lds_void*)&Bb[buf * 12288 + rl * 64], 16, 0, 0);
  };

  f32x4 acc[4][6];
#pragma unroll
  for (int mi = 0; mi < 4; ++mi)
#pragma unroll
    for (int ni = 0; ni < 6; ++ni) acc[mi][ni] = (f32x4){0.f, 0.f, 0.f, 0.f};

  // prologue: A(0) x4, B(0) x3, A(1) x4  -> 11 in flight (ledger base)
#pragma unroll
  for (int u = 0; u < 4; ++u) stageA(0, u, 0);
#pragma unroll
  for (int u = 0; u < 3; ++u) stageB(0, u, 0);
#pragma unroll
  for (int u = 0; u < 4; ++u) stageA(1, u, 1);

  for (int t = 0; t < NKT; ++t) {
    const int  ab   = t % 3;
    const int  bb   = t & 1;
    const bool preB = (t + 1) < NKT;
    const bool preA = (t + 2) < NKT;
    const int  ab2  = (t + 2) % 3;

    if (t < NKT - 1) asm volatile("s_waitcnt vmcnt(4)" ::: "memory");
    else             asm volatile("s_waitcnt vmcnt(0)" ::: "memory");
    __builtin_amdgcn_s_barrier();

    u16x8 af[2], bfr[6];
#pragma unroll
    for (int ph = 0; ph < 4; ++ph) {
      const int ks = ph >> 1;
      const int mh = ph & 1;
      const int gsw = ((ks * 4 + lg) ^ (lc & 7)) << 3;
      if (mh == 0) {
#pragma unroll
        for (int ni = 0; ni < 6; ++ni)
          bfr[ni] = *(const u16x8*)&Bb[bb * 12288 + (wn * 96 + ni * 16 + lc) * 64 + gsw];
      }
#pragma unroll
      for (int i = 0; i < 2; ++i)
        af[i] = *(const u16x8*)&Ab[ab * 16384 + (wm * 64 + (mh * 2 + i) * 16 + lc) * 64 + gsw];

      if (ph == 0 && preB) { stageB(bb ^ 1, 0, t + 1); stageB(bb ^ 1, 1, t + 1); }
      if (ph == 1) { if (preB) stageB(bb ^ 1, 2, t + 1); if (preA) stageA(ab2, 0, t + 2); }
      if (ph == 2 && preA) { stageA(ab2, 1, t + 2); stageA(ab2, 2, t + 2); }
      if (ph == 3 && preA) { stageA(ab2, 3, t + 2); }

      __builtin_amdgcn_s_barrier();
      asm volatile("s_waitcnt lgkmcnt(0)" ::: "memory");
      __builtin_amdgcn_sched_barrier(0);
      __builtin_amdgcn_s_setprio(1);
#pragma unroll
      for (int i = 0; i < 2; ++i)
#pragma unroll
        for (int ni = 0; ni < 6; ++ni)
          acc[mh * 2 + i][ni] = mfma_bf16(af[i], bfr[ni], acc[mh * 2 + i][ni]);
      __builtin_amdgcn_s_setprio(0);
      __builtin_amdgcn_sched_barrier(0);
      if (ph < 3) __builtin_amdgcn_s_barrier();
    }
  }
  __syncthreads();   // all LDS reads retired before qkvT aliases Ab/Bb

  // ---- epilogue: acc -> bf16 -> qkvT[256][200] ----
#pragma unroll
  for (int mi = 0; mi < 4; ++mi)
#pragma unroll
    for (int ni = 0; ni < 6; ++ni) {
      const int col = wn * 96 + ni * 16 + lc;
      const int rb  = wm * 64 + mi * 16 + lg * 4;
#pragma unroll
      for (int r = 0; r < 4; ++r)
        qkvT[(rb + r) * 200 + col] = f2bf(acc[mi][ni][r]);
    }
  __syncthreads();

  // ---- attention (verified): wave -> 2 tokens ----
  const float scale = 0.125f;
  const f32x4 zf = {0.f, 0.f, 0.f, 0.f};
#pragma unroll
  for (int tt = 0; tt < 2; ++tt) {
    const int tok = wid * 2 + tt;
    const int rb  = tok * 16;
    const int qb  = (rb + lc) * 200;

    u16x8 aq0 = *(const u16x8*)&qkvT[qb + 0  + lg * 8];
    u16x8 aq1 = *(const u16x8*)&qkvT[qb + 32 + lg * 8];
    u16x8 bk0 = *(const u16x8*)&qkvT[qb + 64 + lg * 8];
    u16x8 bk1 = *(const u16x8*)&qkvT[qb + 96 + lg * 8];
    f32x4 s = mfma_bf16(aq0, bk0, zf);
    s = mfma_bf16(aq1, bk1, s);

    const int pb = wid * 512 + tt * 256;
#pragma unroll
    for (int r = 0; r < 4; ++r) {
      const int i = lg * 4 + r;
      float sv = s[r] * scale + pos_bias[h * 256 + i * 16 + lc];
      if (lc > i) sv = -1e30f;
      float m = sv;
#pragma unroll
      for (int off = 8; off >= 1; off >>= 1) m = fmaxf(m, __shfl_xor(m, off));
      float e = __expf(sv - m);
      float sm = e;
#pragma unroll
      for (int off = 8; off >= 1; off >>= 1) sm += __shfl_xor(sm, off);
      Pl[pb + i * 16 + lc] = f2bf(e / sm);
    }
    asm volatile("s_waitcnt lgkmcnt(0)" ::: "memory");

    u16x8 ap = {0, 0, 0, 0, 0, 0, 0, 0};
    if (lane < 32) ap = *(const u16x8*)&Pl[pb + lc * 16 + lg * 8];

#pragma unroll
    for (int nd = 0; nd < 4; ++nd) {
      u16x8 bv = {0, 0, 0, 0, 0, 0, 0, 0};
      if (lane < 32) {
#pragma unroll
        for (int jj = 0; jj < 8; ++jj) {
          const int j = lg * 8 + jj;
          bv[jj] = qkvT[(rb + j) * 200 + 128 + nd * 16 + lc];
        }
      }
      f32x4 o = mfma_bf16(ap, bv, zf);
#pragma unroll
      for (int r = 0; r < 4; ++r) {
        const int i = lg * 4 + r;
        attnbuf[(size_t)(row0 + rb + i) * 512 + h * 64 + nd * 16 + lc] = f2bf(o[r]);
      }
    }
  }
}

// -------- GEMM2: out = attnbuf @ Wo_t^T + bo, 256x128, counted-vmcnt -----
// Same ledger: A ring-3, B ring-2 (2 units), tile-top in-flight 10 ->
// vmcnt(4).  Issue: ph0:B0,B1(t+1) ph1:A0,A1(t+2) ph2:A2,A3(t+2).
__global__ __launch_bounds__(512, 2)
void gemm_out(const u16* __restrict__ A, const u16* __restrict__ Bt,
              float* __restrict__ C, const float* __restrict__ bias) {
  __shared__ __attribute__((aligned(16))) u16 smem[65536];  // Ab[3][16384] | Bb[2][8192]
  u16* Ab = smem;
  u16* Bb = smem + 49152;

  const int tid  = threadIdx.x;
  const int lane = tid & 63;
  const int wid  = tid >> 6;
  const int wm   = wid >> 1;        // 0..3 (64-row band)
  const int wn   = wid & 1;         // 0..1 (64-col band)
  const int lg   = lane >> 4;
  const int lc   = lane & 15;
  const int srow = lane >> 3;
  const int sg   = (lane & 7) ^ srow;

  const int nwg  = gridDim.x;       // 1024
  const int cpx  = nwg >> 3;
  const int flat = blockIdx.x;
  const int swz  = (flat & 7) * cpx + (flat >> 3);
  const int mt   = swz >> 2;
  const int nt   = swz & 3;
  const int row0 = mt * 256, col0 = nt * 128;

  auto stageA = [&](int buf, int unit, int kt) {
    const int rl = unit * 64 + wid * 8;
    const u16* src = A + (size_t)(row0 + rl + srow) * KDIM + kt * 64 + sg * 8;
    __builtin_amdgcn_global_load_lds((gconst_void*)src,
                                     (lds_void*)&Ab[buf * 16384 + rl * 64], 16, 0, 0);
  };
  auto stageB = [&](int buf, int unit, int kt) {
    const int rl = unit * 64 + wid * 8;
    const u16* src = Bt + (size_t)(col0 + rl + srow) * KDIM + kt * 64 + sg * 8;
    __builtin_amdgcn_global_load_lds((gconst_void*)src,
                                     (lds_void*)&Bb[buf * 8192 + rl * 64], 16, 0, 0);
  };

  f32x4 acc[4][4];
#pragma unroll
  for (int mi = 0; mi < 4; ++mi)
#pragma unroll
    for (int ni = 0; ni < 4; ++ni) acc[mi][ni] = (f32x4){0.f, 0.f, 0.f, 0.f};

  // prologue: A(0) x4, B(0) x2, A(1) x4 -> 10 in flight
#pragma unroll
  for (int u = 0; u < 4; ++u) stageA(0, u, 0);
#pragma unroll
  for (int u = 0; u < 2; ++u) stageB(0, u, 0);
#pragma unroll
  for (int u = 0; u < 4; ++u) stageA(1, u, 1);

  for (int t = 0; t < NKT; ++t) {
    const int  ab   = t % 3;
    const int  bb   = t & 1;
    const bool preB = (t + 1) < NKT;
    const bool preA = (t + 2) < NKT;
    const int  ab2  = (t + 2) % 3;

    if (t < NKT - 1) asm volatile("s_waitcnt vmcnt(4)" ::: "memory");
    else             asm volatile("s_waitcnt vmcnt(0)" ::: "memory");
    __builtin_amdgcn_s_barrier();

    u16x8 af[2], bfr[4];
#pragma unroll
    for (int ph = 0; ph < 4; ++ph) {
      const int ks = ph >> 1;
      const int mh = ph & 1;
      const int gsw = ((ks * 4 + lg) ^ (lc & 7)) << 3;
      if (mh == 0) {
#pragma unroll
        for (int ni = 0; ni < 4; ++ni)
          bfr[ni] = *(const u16x8*)&Bb[bb * 8192 + (wn * 64 + ni * 16 + lc) * 64 + gsw];
      }
#pragma unroll
      for (int i = 0; i < 2; ++i)
        af[i] = *(const u16x8*)&Ab[ab * 16384 + (wm * 64 + (mh * 2 + i) * 16 + lc) * 64 + gsw];

      if (ph == 0 && preB) { stageB(bb ^ 1, 0, t + 1); stageB(bb ^ 1, 1, t + 1); }
      if (ph == 1 && preA) { stageA(ab2, 0, t + 2); stageA(ab2, 1, t + 2); }
      if (ph == 2 && preA) { stageA(ab2, 2, t + 2); stageA(ab2, 3, t + 2); }

      __builtin_amdgcn_s_barrier();
      asm volatile("s_waitcnt lgkmcnt(0)" ::: "memory");
      __builtin_amdgcn_sched_barrier(0);
      __builtin_amdgcn_s_setprio(1);
#pragma unroll
      for (int i = 0; i < 2; ++i)
#pragma unroll
        for (int ni = 0; ni < 4; ++ni)
          acc[mh * 2 + i][ni] = mfma_bf16(af[i], bfr[ni], acc[mh * 2 + i][ni]);
      __builtin_amdgcn_s_setprio(0);
      __builtin_amdgcn_sched_barrier(0);
      if (ph < 3) __builtin_amdgcn_s_barrier();
    }
  }

  // epilogue (global only)
  const int gmb = row0 + wm * 64;
  const int gnb = col0 + wn * 64;
#pragma unroll
  for (int mi = 0; mi < 4; ++mi)
#pragma unroll
    for (int ni = 0; ni < 4; ++ni) {
      const int gm = gmb + mi * 16 + lg * 4;
      const int gn = gnb + ni * 16 + lc;
      const float bv = bias[gn];
      f32x4 v = acc[mi][ni];
#pragma unroll
      for (int r = 0; r < 4; ++r) C[(size_t)(gm + r) * 512 + gn] = v[r] + bv;
    }
}

// ---------------- launch ----------------
extern "C" void kernel_launch(void* const* d_in, const int* in_sizes, int n_in,
                              void* d_out, int out_size, void* d_ws, size_t ws_size,
                              hipStream_t stream) {
  const float* x        = (const float*)d_in[0];
  const float* pos_bias = (const float*)d_in[1];
  const float* Wq       = (const float*)d_in[2];
  const float* Wk       = (const float*)d_in[3];
  const float* Wv       = (const float*)d_in[4];
  const float* Wo       = (const float*)d_in[5];
  const float* bo       = (const float*)d_in[6];
  float* out            = (float*)d_out;

  u16* xb      = (u16*)d_ws;                           // [65536][512]
  u16* attnbuf = xb + (size_t)M_ROWS * 512;            // [65536][512]
  u16* Wo_t    = attnbuf + (size_t)M_ROWS * 512;       // [512][512]
  u16* Wqkv_t  = (u16*)d_out;                          // [1536][512] (dead until GEMM2)

  conv_x<<<dim3(M_ROWS * KDIM / (256 * 8)), dim3(256), 0, stream>>>(x, xb);
  convW_qkv_t<<<dim3(48, 16), dim3(256), 0, stream>>>(Wq, Wk, Wv, Wqkv_t);
  gemm_qkv_attn<<<dim3(2048), dim3(512), 0, stream>>>(xb, Wqkv_t, pos_bias, attnbuf);
  convWo_t<<<dim3(16, 16), dim3(256), 0, stream>>>(Wo, Wo_t);
  gemm_out<<<dim3(1024), dim3(512), 0, stream>>>(attnbuf, Wo_t, out, bo);
}

// Round 12
// 220.644 us; speedup vs baseline: 1.5368x; 1.0164x over previous
//
#include <hip/hip_runtime.h>

typedef unsigned short u16;
typedef __attribute__((ext_vector_type(8))) unsigned short u16x8;
typedef __attribute__((ext_vector_type(8))) __bf16 bf16x8;
typedef __attribute__((ext_vector_type(4))) float f32x4;

#define M_ROWS 65536   // b*s*f
#define KDIM   512
#define NKT    8       // KDIM / 64

typedef __attribute__((address_space(1))) const void gconst_void;
typedef __attribute__((address_space(3))) void lds_void;

static __device__ __forceinline__ u16 f2bf(float f) {
  unsigned u = __builtin_bit_cast(unsigned, f);
  u += 0x7FFFu + ((u >> 16) & 1u);
  return (u16)(u >> 16);
}

static __device__ __forceinline__ f32x4 mfma_bf16(u16x8 a, u16x8 b, f32x4 c) {
  return __builtin_amdgcn_mfma_f32_16x16x32_bf16(
      __builtin_bit_cast(bf16x8, a), __builtin_bit_cast(bf16x8, b), c, 0, 0, 0);
}

// ---------------- fp32 -> bf16 convert (x) ----------------
__global__ void conv_x(const float* __restrict__ x, u16* __restrict__ xb) {
  const size_t t = (size_t)blockIdx.x * 256 + threadIdx.x;
  f32x4 a = *(const f32x4*)(x + t * 8);
  f32x4 b = *(const f32x4*)(x + t * 8 + 4);
  u16x8 w;
#pragma unroll
  for (int e = 0; e < 4; ++e) { w[e] = f2bf(a[e]); w[e + 4] = f2bf(b[e]); }
  *(u16x8*)(xb + t * 8) = w;
}

// ------ weight transpose+convert, LDS-tiled ------
__global__ void convW_qkv_t(const float* __restrict__ Wq, const float* __restrict__ Wk,
                            const float* __restrict__ Wv, u16* __restrict__ Wt) {
  __shared__ float tile[32][33];
  const int bn = blockIdx.x * 32;
  const int bk = blockIdx.y * 32;
  const int tx = threadIdx.x & 31, ty = threadIdx.x >> 5;
  const float* W = (bn < 512) ? Wq : ((bn < 1024) ? Wk : Wv);
  const int coln = bn & 511;
#pragma unroll
  for (int r = 0; r < 32; r += 8)
    tile[ty + r][tx] = W[(size_t)(bk + ty + r) * 512 + coln + tx];
  __syncthreads();
#pragma unroll
  for (int r = 0; r < 32; r += 8)
    Wt[(size_t)(bn + ty + r) * 512 + bk + tx] = f2bf(tile[tx][ty + r]);
}

__global__ void convWo_t(const float* __restrict__ Wo, u16* __restrict__ Wt) {
  __shared__ float tile[32][33];
  const int bn = blockIdx.x * 32;
  const int bk = blockIdx.y * 32;
  const int tx = threadIdx.x & 31, ty = threadIdx.x >> 5;
#pragma unroll
  for (int r = 0; r < 32; r += 8)
    tile[ty + r][tx] = Wo[(size_t)(bk + ty + r) * 512 + bn + tx];
  __syncthreads();
#pragma unroll
  for (int r = 0; r < 32; r += 8)
    Wt[(size_t)(bn + ty + r) * 512 + bk + tx] = f2bf(tile[tx][ty + r]);
}

// -------- FUSED qkv projection (one head) + attention, barrier-light ------
// r11 counted-vmcnt ledger, with all intra-tile barriers REMOVED: staging
// writes only ring buffers t+1/t+2 (disjoint from the tile-t read buffer),
// so the only required sync is the tile-top per-wave vmcnt + one barrier.
// Compiler free-schedules the 2x(10 ds_read + 24 MFMA) tile body.
// Ledger: prologue A(0)4+B(0)3+A(1)4 = 11 in flight; per tile issue
// B(t+1)x3 + A(t+2)x4 after the barrier; tile-top vmcnt(4) retires exactly
// tile t's 7 units (leaves A(t+1)x4).
__global__ __launch_bounds__(512, 2)
void gemm_qkv_attn(const u16* __restrict__ A, const u16* __restrict__ Wt,
                   const float* __restrict__ pos_bias, u16* __restrict__ attnbuf) {
  // smem u16[73728] = 144 KiB: Ab[3][16384] | Bb[2][12288]
  // post-loop alias: qkvT[256][200] at 0, Pl[4096] at 51200
  __shared__ __attribute__((aligned(16))) u16 smem[73728];
  u16* Ab   = smem;
  u16* Bb   = smem + 49152;
  u16* qkvT = smem;
  u16* Pl   = smem + 51200;

  const int tid  = threadIdx.x;
  const int lane = tid & 63;
  const int wid  = tid >> 6;        // 0..7
  const int wm   = wid >> 1;        // 0..3 (64-row band)
  const int wn   = wid & 1;         // 0..1 (96-col band)
  const int lg   = lane >> 4;
  const int lc   = lane & 15;
  const int srow = lane >> 3;       // 0..7
  const int sg   = (lane & 7) ^ srow;

  const int nwg  = gridDim.x;
  const int cpx  = nwg >> 3;
  const int flat = blockIdx.x;
  const int swz  = (flat & 7) * cpx + (flat >> 3);
  const int mt   = swz >> 3;
  const int h    = swz & 7;
  const int row0 = mt * 256;

  auto stageA = [&](int buf, int unit, int kt) {
    const int rl = unit * 64 + wid * 8;
    const u16* src = A + (size_t)(row0 + rl + srow) * KDIM + kt * 64 + sg * 8;
    __builtin_amdgcn_global_load_lds((gconst_void*)src,
                                     (lds_void*)&Ab[buf * 16384 + rl * 64], 16, 0, 0);
  };
  auto stageB = [&](int buf, int unit, int kt) {
    const int rl = unit * 64 + wid * 8;
    const int grow = unit * 512 + h * 64 + wid * 8 + srow;
    const u16* src = Wt + (size_t)grow * KDIM + kt * 64 + sg * 8;
    __builtin_amdgcn_global_load_lds((gconst_void*)src,
                                     (lds_void*)&Bb[buf * 12288 + rl * 64], 16, 0, 0);
  };

  f32x4 acc[4][6];
#pragma unroll
  for (int mi = 0; mi < 4; ++mi)
#pragma unroll
    for (int ni = 0; ni < 6; ++ni) acc[mi][ni] = (f32x4){0.f, 0.f, 0.f, 0.f};

  // prologue: A(0) x4, B(0) x3, A(1) x4 -> 11 in flight
#pragma unroll
  for (int u = 0; u < 4; ++u) stageA(0, u, 0);
#pragma unroll
  for (int u = 0; u < 3; ++u) stageB(0, u, 0);
#pragma unroll
  for (int u = 0; u < 4; ++u) stageA(1, u, 1);

  for (int t = 0; t < NKT; ++t) {
    const int  ab   = t % 3;
    const int  bb   = t & 1;
    const bool preB = (t + 1) < NKT;
    const bool preA = (t + 2) < NKT;
    const int  ab2  = (t + 2) % 3;

    if (t < NKT - 1) asm volatile("s_waitcnt vmcnt(4)" ::: "memory");
    else             asm volatile("s_waitcnt vmcnt(0)" ::: "memory");
    __builtin_amdgcn_s_barrier();

    if (preB) { stageB(bb ^ 1, 0, t + 1); stageB(bb ^ 1, 1, t + 1); stageB(bb ^ 1, 2, t + 1); }
    if (preA) { stageA(ab2, 0, t + 2); stageA(ab2, 1, t + 2);
                stageA(ab2, 2, t + 2); stageA(ab2, 3, t + 2); }

#pragma unroll
    for (int ks = 0; ks < 2; ++ks) {
      const int gsw = ((ks * 4 + lg) ^ (lc & 7)) << 3;
      u16x8 bfr[6], af[4];
#pragma unroll
      for (int ni = 0; ni < 6; ++ni)
        bfr[ni] = *(const u16x8*)&Bb[bb * 12288 + (wn * 96 + ni * 16 + lc) * 64 + gsw];
#pragma unroll
      for (int i = 0; i < 4; ++i)
        af[i] = *(const u16x8*)&Ab[ab * 16384 + (wm * 64 + i * 16 + lc) * 64 + gsw];
#pragma unroll
      for (int i = 0; i < 4; ++i)
#pragma unroll
        for (int ni = 0; ni < 6; ++ni)
          acc[i][ni] = mfma_bf16(af[i], bfr[ni], acc[i][ni]);
    }
  }
  __syncthreads();   // all LDS reads retired before qkvT aliases Ab/Bb

  // ---- epilogue: acc -> bf16 -> qkvT[256][200] ----
#pragma unroll
  for (int mi = 0; mi < 4; ++mi)
#pragma unroll
    for (int ni = 0; ni < 6; ++ni) {
      const int col = wn * 96 + ni * 16 + lc;
      const int rb  = wm * 64 + mi * 16 + lg * 4;
#pragma unroll
      for (int r = 0; r < 4; ++r)
        qkvT[(rb + r) * 200 + col] = f2bf(acc[mi][ni][r]);
    }
  __syncthreads();

  // ---- attention (verified): wave -> 2 tokens ----
  const float scale = 0.125f;
  const f32x4 zf = {0.f, 0.f, 0.f, 0.f};
#pragma unroll
  for (int tt = 0; tt < 2; ++tt) {
    const int tok = wid * 2 + tt;
    const int rb  = tok * 16;
    const int qb  = (rb + lc) * 200;

    u16x8 aq0 = *(const u16x8*)&qkvT[qb + 0  + lg * 8];
    u16x8 aq1 = *(const u16x8*)&qkvT[qb + 32 + lg * 8];
    u16x8 bk0 = *(const u16x8*)&qkvT[qb + 64 + lg * 8];
    u16x8 bk1 = *(const u16x8*)&qkvT[qb + 96 + lg * 8];
    f32x4 s = mfma_bf16(aq0, bk0, zf);
    s = mfma_bf16(aq1, bk1, s);

    const int pb = wid * 512 + tt * 256;
#pragma unroll
    for (int r = 0; r < 4; ++r) {
      const int i = lg * 4 + r;
      float sv = s[r] * scale + pos_bias[h * 256 + i * 16 + lc];
      if (lc > i) sv = -1e30f;
      float m = sv;
#pragma unroll
      for (int off = 8; off >= 1; off >>= 1) m = fmaxf(m, __shfl_xor(m, off));
      float e = __expf(sv - m);
      float sm = e;
#pragma unroll
      for (int off = 8; off >= 1; off >>= 1) sm += __shfl_xor(sm, off);
      Pl[pb + i * 16 + lc] = f2bf(e / sm);
    }
    asm volatile("s_waitcnt lgkmcnt(0)" ::: "memory");

    u16x8 ap = {0, 0, 0, 0, 0, 0, 0, 0};
    if (lane < 32) ap = *(const u16x8*)&Pl[pb + lc * 16 + lg * 8];

#pragma unroll
    for (int nd = 0; nd < 4; ++nd) {
      u16x8 bv = {0, 0, 0, 0, 0, 0, 0, 0};
      if (lane < 32) {
#pragma unroll
        for (int jj = 0; jj < 8; ++jj) {
          const int j = lg * 8 + jj;
          bv[jj] = qkvT[(rb + j) * 200 + 128 + nd * 16 + lc];
        }
      }
      f32x4 o = mfma_bf16(ap, bv, zf);
#pragma unroll
      for (int r = 0; r < 4; ++r) {
        const int i = lg * 4 + r;
        attnbuf[(size_t)(row0 + rb + i) * 512 + h * 64 + nd * 16 + lc] = f2bf(o[r]);
      }
    }
  }
}

// -------- GEMM2: out = attnbuf @ Wo_t^T + bo, 256x128, barrier-light -----
// Same ledger (prologue 10 in flight; issue B(t+1)x2 + A(t+2)x4 per tile;
// tile-top vmcnt(4)); intra-tile barriers removed as above.
__global__ __launch_bounds__(512, 2)
void gemm_out(const u16* __restrict__ A, const u16* __restrict__ Bt,
              float* __restrict__ C, const float* __restrict__ bias) {
  __shared__ __attribute__((aligned(16))) u16 smem[65536];  // Ab[3][16384] | Bb[2][8192]
  u16* Ab = smem;
  u16* Bb = smem + 49152;

  const int tid  = threadIdx.x;
  const int lane = tid & 63;
  const int wid  = tid >> 6;
  const int wm   = wid >> 1;        // 0..3 (64-row band)
  const int wn   = wid & 1;         // 0..1 (64-col band)
  const int lg   = lane >> 4;
  const int lc   = lane & 15;
  const int srow = lane >> 3;
  const int sg   = (lane & 7) ^ srow;

  const int nwg  = gridDim.x;       // 1024
  const int cpx  = nwg >> 3;
  const int flat = blockIdx.x;
  const int swz  = (flat & 7) * cpx + (flat >> 3);
  const int mt   = swz >> 2;
  const int nt   = swz & 3;
  const int row0 = mt * 256, col0 = nt * 128;

  auto stageA = [&](int buf, int unit, int kt) {
    const int rl = unit * 64 + wid * 8;
    const u16* src = A + (size_t)(row0 + rl + srow) * KDIM + kt * 64 + sg * 8;
    __builtin_amdgcn_global_load_lds((gconst_void*)src,
                                     (lds_void*)&Ab[buf * 16384 + rl * 64], 16, 0, 0);
  };
  auto stageB = [&](int buf, int unit, int kt) {
    const int rl = unit * 64 + wid * 8;
    const u16* src = Bt + (size_t)(col0 + rl + srow) * KDIM + kt * 64 + sg * 8;
    __builtin_amdgcn_global_load_lds((gconst_void*)src,
                                     (lds_void*)&Bb[buf * 8192 + rl * 64], 16, 0, 0);
  };

  f32x4 acc[4][4];
#pragma unroll
  for (int mi = 0; mi < 4; ++mi)
#pragma unroll
    for (int ni = 0; ni < 4; ++ni) acc[mi][ni] = (f32x4){0.f, 0.f, 0.f, 0.f};

  // prologue: A(0) x4, B(0) x2, A(1) x4 -> 10 in flight
#pragma unroll
  for (int u = 0; u < 4; ++u) stageA(0, u, 0);
#pragma unroll
  for (int u = 0; u < 2; ++u) stageB(0, u, 0);
#pragma unroll
  for (int u = 0; u < 4; ++u) stageA(1, u, 1);

  for (int t = 0; t < NKT; ++t) {
    const int  ab   = t % 3;
    const int  bb   = t & 1;
    const bool preB = (t + 1) < NKT;
    const bool preA = (t + 2) < NKT;
    const int  ab2  = (t + 2) % 3;

    if (t < NKT - 1) asm volatile("s_waitcnt vmcnt(4)" ::: "memory");
    else             asm volatile("s_waitcnt vmcnt(0)" ::: "memory");
    __builtin_amdgcn_s_barrier();

    if (preB) { stageB(bb ^ 1, 0, t + 1); stageB(bb ^ 1, 1, t + 1); }
    if (preA) { stageA(ab2, 0, t + 2); stageA(ab2, 1, t + 2);
                stageA(ab2, 2, t + 2); stageA(ab2, 3, t + 2); }

#pragma unroll
    for (int ks = 0; ks < 2; ++ks) {
      const int gsw = ((ks * 4 + lg) ^ (lc & 7)) << 3;
      u16x8 bfr[4], af[4];
#pragma unroll
      for (int ni = 0; ni < 4; ++ni)
        bfr[ni] = *(const u16x8*)&Bb[bb * 8192 + (wn * 64 + ni * 16 + lc) * 64 + gsw];
#pragma unroll
      for (int i = 0; i < 4; ++i)
        af[i] = *(const u16x8*)&Ab[ab * 16384 + (wm * 64 + i * 16 + lc) * 64 + gsw];
#pragma unroll
      for (int i = 0; i < 4; ++i)
#pragma unroll
        for (int ni = 0; ni < 4; ++ni)
          acc[i][ni] = mfma_bf16(af[i], bfr[ni], acc[i][ni]);
    }
  }

  // epilogue (global only)
  const int gmb = row0 + wm * 64;
  const int gnb = col0 + wn * 64;
#pragma unroll
  for (int mi = 0; mi < 4; ++mi)
#pragma unroll
    for (int ni = 0; ni < 4; ++ni) {
      const int gm = gmb + mi * 16 + lg * 4;
      const int gn = gnb + ni * 16 + lc;
      const float bv = bias[gn];
      f32x4 v = acc[mi][ni];
#pragma unroll
      for (int r = 0; r < 4; ++r) C[(size_t)(gm + r) * 512 + gn] = v[r] + bv;
    }
}

// ---------------- launch ----------------
extern "C" void kernel_launch(void* const* d_in, const int* in_sizes, int n_in,
                              void* d_out, int out_size, void* d_ws, size_t ws_size,
                              hipStream_t stream) {
  const float* x        = (const float*)d_in[0];
  const float* pos_bias = (const float*)d_in[1];
  const float* Wq       = (const float*)d_in[2];
  const float* Wk       = (const float*)d_in[3];
  const float* Wv       = (const float*)d_in[4];
  const float* Wo       = (const float*)d_in[5];
  const float* bo       = (const float*)d_in[6];
  float* out            = (float*)d_out;

  u16* xb      = (u16*)d_ws;                           // [65536][512]
  u16* attnbuf = xb + (size_t)M_ROWS * 512;            // [65536][512]
  u16* Wo_t    = attnbuf + (size_t)M_ROWS * 512;       // [512][512]
  u16* Wqkv_t  = (u16*)d_out;                          // [1536][512] (dead until GEMM2)

  conv_x<<<dim3(M_ROWS * KDIM / (256 * 8)), dim3(256), 0, stream>>>(x, xb);
  convW_qkv_t<<<dim3(48, 16), dim3(256), 0, stream>>>(Wq, Wk, Wv, Wqkv_t);
  gemm_qkv_attn<<<dim3(2048), dim3(512), 0, stream>>>(xb, Wqkv_t, pos_bias, attnbuf);
  convWo_t<<<dim3(16, 16), dim3(256), 0, stream>>>(Wo, Wo_t);
  gemm_out<<<dim3(1024), dim3(512), 0, stream>>>(attnbuf, Wo_t, out, bo);
}

// Round 13
// 210.657 us; speedup vs baseline: 1.6096x; 1.0474x over previous
//
#include <hip/hip_runtime.h>

typedef unsigned short u16;
typedef __attribute__((ext_vector_type(8))) unsigned short u16x8;
typedef __attribute__((ext_vector_type(8))) __bf16 bf16x8;
typedef __attribute__((ext_vector_type(4))) float f32x4;

#define M_ROWS 65536   // b*s*f
#define KDIM   512
#define NKT    8       // KDIM / 64

typedef __attribute__((address_space(1))) const void gconst_void;
typedef __attribute__((address_space(3))) void lds_void;

static __device__ __forceinline__ u16 f2bf(float f) {
  unsigned u = __builtin_bit_cast(unsigned, f);
  u += 0x7FFFu + ((u >> 16) & 1u);
  return (u16)(u >> 16);
}

static __device__ __forceinline__ f32x4 mfma_bf16(u16x8 a, u16x8 b, f32x4 c) {
  return __builtin_amdgcn_mfma_f32_16x16x32_bf16(
      __builtin_bit_cast(bf16x8, a), __builtin_bit_cast(bf16x8, b), c, 0, 0, 0);
}

// ---------------- fp32 -> bf16 convert (x) ----------------
__global__ void conv_x(const float* __restrict__ x, u16* __restrict__ xb) {
  const size_t t = (size_t)blockIdx.x * 256 + threadIdx.x;
  f32x4 a = *(const f32x4*)(x + t * 8);
  f32x4 b = *(const f32x4*)(x + t * 8 + 4);
  u16x8 w;
#pragma unroll
  for (int e = 0; e < 4; ++e) { w[e] = f2bf(a[e]); w[e + 4] = f2bf(b[e]); }
  *(u16x8*)(xb + t * 8) = w;
}

// ------ weight transpose+convert, LDS-tiled ------
__global__ void convW_qkv_t(const float* __restrict__ Wq, const float* __restrict__ Wk,
                            const float* __restrict__ Wv, u16* __restrict__ Wt) {
  __shared__ float tile[32][33];
  const int bn = blockIdx.x * 32;
  const int bk = blockIdx.y * 32;
  const int tx = threadIdx.x & 31, ty = threadIdx.x >> 5;
  const float* W = (bn < 512) ? Wq : ((bn < 1024) ? Wk : Wv);
  const int coln = bn & 511;
#pragma unroll
  for (int r = 0; r < 32; r += 8)
    tile[ty + r][tx] = W[(size_t)(bk + ty + r) * 512 + coln + tx];
  __syncthreads();
#pragma unroll
  for (int r = 0; r < 32; r += 8)
    Wt[(size_t)(bn + ty + r) * 512 + bk + tx] = f2bf(tile[tx][ty + r]);
}

__global__ void convWo_t(const float* __restrict__ Wo, u16* __restrict__ Wt) {
  __shared__ float tile[32][33];
  const int bn = blockIdx.x * 32;
  const int bk = blockIdx.y * 32;
  const int tx = threadIdx.x & 31, ty = threadIdx.x >> 5;
#pragma unroll
  for (int r = 0; r < 32; r += 8)
    tile[ty + r][tx] = Wo[(size_t)(bk + ty + r) * 512 + bn + tx];
  __syncthreads();
#pragma unroll
  for (int r = 0; r < 32; r += 8)
    Wt[(size_t)(bn + ty + r) * 512 + bk + tx] = f2bf(tile[tx][ty + r]);
}

// -------- FUSED qkv projection (one head) + attention, BM=128, 2 blk/CU ---
// 8 waves = 2M x 4N (wave tile 64x48, acc 4x3).  LDS exactly 80 KiB
// (Ab[2][128x64] 32K + Bb[2][192x64] 48K) -> 2 resident blocks/CU; the
// co-resident block covers prologue fill, tile-top drains, and the serial
// attention tail (m114 cross-block overlap -- the ingredient every 256^2
// 1-blk/CU variant lacked).  Sync = proven simple form: tile-top vmcnt(0)
// + barrier; stage(t+1) issued right after.  Post-loop alias:
// qkvT[128][200] (50K) + Pl[2048] -- fits under the 80K allocation.
__global__ __launch_bounds__(512, 4)
void gemm_qkv_attn(const u16* __restrict__ A, const u16* __restrict__ Wt,
                   const float* __restrict__ pos_bias, u16* __restrict__ attnbuf) {
  __shared__ __attribute__((aligned(16))) u16 smem[40960];  // 80 KiB
  u16* Ab   = smem;            // [2][8192]
  u16* Bb   = smem + 16384;    // [2][12288]
  u16* qkvT = smem;            // [128][200] = 25600
  u16* Pl   = smem + 25600;    // [8][256]  = 2048

  const int tid  = threadIdx.x;
  const int lane = tid & 63;
  const int wid  = tid >> 6;        // 0..7
  const int wm   = wid >> 2;        // 0..1 (64-row band)
  const int wn   = wid & 3;         // 0..3 (48-col band)
  const int lg   = lane >> 4;
  const int lc   = lane & 15;
  const int srow = lane >> 3;       // 0..7
  const int sg   = (lane & 7) ^ srow;

  const int nwg  = gridDim.x;       // 4096
  const int cpx  = nwg >> 3;
  const int flat = blockIdx.x;
  const int swz  = (flat & 7) * cpx + (flat >> 3);
  const int mt   = swz >> 3;
  const int h    = swz & 7;
  const int row0 = mt * 128;

  // A: 2 units x 64 rows; B: 3 units x 64 rows (rows of head-h's q|k|v)
  auto stageA = [&](int buf, int unit, int kt) {
    const int rl = unit * 64 + wid * 8;
    const u16* src = A + (size_t)(row0 + rl + srow) * KDIM + kt * 64 + sg * 8;
    __builtin_amdgcn_global_load_lds((gconst_void*)src,
                                     (lds_void*)&Ab[buf * 8192 + rl * 64], 16, 0, 0);
  };
  auto stageB = [&](int buf, int unit, int kt) {
    const int rl = unit * 64 + wid * 8;
    const int grow = unit * 512 + h * 64 + wid * 8 + srow;
    const u16* src = Wt + (size_t)grow * KDIM + kt * 64 + sg * 8;
    __builtin_amdgcn_global_load_lds((gconst_void*)src,
                                     (lds_void*)&Bb[buf * 12288 + rl * 64], 16, 0, 0);
  };

  f32x4 acc[4][3];
#pragma unroll
  for (int mi = 0; mi < 4; ++mi)
#pragma unroll
    for (int ni = 0; ni < 3; ++ni) acc[mi][ni] = (f32x4){0.f, 0.f, 0.f, 0.f};

  // prologue: stage tile 0 into buf 0
  stageA(0, 0, 0); stageA(0, 1, 0);
  stageB(0, 0, 0); stageB(0, 1, 0); stageB(0, 2, 0);
  asm volatile("s_waitcnt vmcnt(0)" ::: "memory");
  __builtin_amdgcn_s_barrier();

  for (int t = 0; t < NKT; ++t) {
    const int  c   = t & 1;
    const bool pre = (t + 1) < NKT;

    if (pre) {
      stageA(c ^ 1, 0, t + 1); stageA(c ^ 1, 1, t + 1);
      stageB(c ^ 1, 0, t + 1); stageB(c ^ 1, 1, t + 1); stageB(c ^ 1, 2, t + 1);
    }

#pragma unroll
    for (int ks = 0; ks < 2; ++ks) {
      const int gsw = ((ks * 4 + lg) ^ (lc & 7)) << 3;
      u16x8 bfr[3], af[4];
#pragma unroll
      for (int ni = 0; ni < 3; ++ni)
        bfr[ni] = *(const u16x8*)&Bb[c * 12288 + (wn * 48 + ni * 16 + lc) * 64 + gsw];
#pragma unroll
      for (int i = 0; i < 4; ++i)
        af[i] = *(const u16x8*)&Ab[c * 8192 + (wm * 64 + i * 16 + lc) * 64 + gsw];
#pragma unroll
      for (int i = 0; i < 4; ++i)
#pragma unroll
        for (int ni = 0; ni < 3; ++ni)
          acc[i][ni] = mfma_bf16(af[i], bfr[ni], acc[i][ni]);
    }

    asm volatile("s_waitcnt vmcnt(0)" ::: "memory");
    __builtin_amdgcn_s_barrier();
  }

  // ---- epilogue: acc -> bf16 -> qkvT[128][200] (aliases Ab/Bb; the loop's
  // final vmcnt(0)+barrier retired all LDS traffic) ----
#pragma unroll
  for (int mi = 0; mi < 4; ++mi)
#pragma unroll
    for (int ni = 0; ni < 3; ++ni) {
      const int col = wn * 48 + ni * 16 + lc;
      const int rb  = wm * 64 + mi * 16 + lg * 4;
#pragma unroll
      for (int r = 0; r < 4; ++r)
        qkvT[(rb + r) * 200 + col] = f2bf(acc[mi][ni][r]);
    }
  __syncthreads();

  // ---- attention (verified math): one token per wave ----
  const float scale = 0.125f;
  const f32x4 zf = {0.f, 0.f, 0.f, 0.f};
  const int rb = wid * 16;
  const int qb = (rb + lc) * 200;

  u16x8 aq0 = *(const u16x8*)&qkvT[qb + 0  + lg * 8];
  u16x8 aq1 = *(const u16x8*)&qkvT[qb + 32 + lg * 8];
  u16x8 bk0 = *(const u16x8*)&qkvT[qb + 64 + lg * 8];
  u16x8 bk1 = *(const u16x8*)&qkvT[qb + 96 + lg * 8];
  f32x4 s = mfma_bf16(aq0, bk0, zf);
  s = mfma_bf16(aq1, bk1, s);

  const int pb = wid * 256;
#pragma unroll
  for (int r = 0; r < 4; ++r) {
    const int i = lg * 4 + r;
    float sv = s[r] * scale + pos_bias[h * 256 + i * 16 + lc];
    if (lc > i) sv = -1e30f;
    float m = sv;
#pragma unroll
    for (int off = 8; off >= 1; off >>= 1) m = fmaxf(m, __shfl_xor(m, off));
    float e = __expf(sv - m);
    float sm = e;
#pragma unroll
    for (int off = 8; off >= 1; off >>= 1) sm += __shfl_xor(sm, off);
    Pl[pb + i * 16 + lc] = f2bf(e / sm);
  }
  asm volatile("s_waitcnt lgkmcnt(0)" ::: "memory");

  u16x8 ap = {0, 0, 0, 0, 0, 0, 0, 0};
  if (lane < 32) ap = *(const u16x8*)&Pl[pb + lc * 16 + lg * 8];

#pragma unroll
  for (int nd = 0; nd < 4; ++nd) {
    u16x8 bv = {0, 0, 0, 0, 0, 0, 0, 0};
    if (lane < 32) {
#pragma unroll
      for (int jj = 0; jj < 8; ++jj) {
        const int j = lg * 8 + jj;
        bv[jj] = qkvT[(rb + j) * 200 + 128 + nd * 16 + lc];
      }
    }
    f32x4 o = mfma_bf16(ap, bv, zf);
#pragma unroll
    for (int r = 0; r < 4; ++r) {
      const int i = lg * 4 + r;
      attnbuf[(size_t)(row0 + rb + i) * 512 + h * 64 + nd * 16 + lc] = f2bf(o[r]);
    }
  }
}

// -------- GEMM2: out = attnbuf @ Wo_t^T + bo, 256x128 (r12 form) -----
__global__ __launch_bounds__(512, 2)
void gemm_out(const u16* __restrict__ A, const u16* __restrict__ Bt,
              float* __restrict__ C, const float* __restrict__ bias) {
  __shared__ __attribute__((aligned(16))) u16 smem[65536];  // Ab[3][16384] | Bb[2][8192]
  u16* Ab = smem;
  u16* Bb = smem + 49152;

  const int tid  = threadIdx.x;
  const int lane = tid & 63;
  const int wid  = tid >> 6;
  const int wm   = wid >> 1;        // 0..3 (64-row band)
  const int wn   = wid & 1;         // 0..1 (64-col band)
  const int lg   = lane >> 4;
  const int lc   = lane & 15;
  const int srow = lane >> 3;
  const int sg   = (lane & 7) ^ srow;

  const int nwg  = gridDim.x;       // 1024
  const int cpx  = nwg >> 3;
  const int flat = blockIdx.x;
  const int swz  = (flat & 7) * cpx + (flat >> 3);
  const int mt   = swz >> 2;
  const int nt   = swz & 3;
  const int row0 = mt * 256, col0 = nt * 128;

  auto stageA = [&](int buf, int unit, int kt) {
    const int rl = unit * 64 + wid * 8;
    const u16* src = A + (size_t)(row0 + rl + srow) * KDIM + kt * 64 + sg * 8;
    __builtin_amdgcn_global_load_lds((gconst_void*)src,
                                     (lds_void*)&Ab[buf * 16384 + rl * 64], 16, 0, 0);
  };
  auto stageB = [&](int buf, int unit, int kt) {
    const int rl = unit * 64 + wid * 8;
    const u16* src = Bt + (size_t)(col0 + rl + srow) * KDIM + kt * 64 + sg * 8;
    __builtin_amdgcn_global_load_lds((gconst_void*)src,
                                     (lds_void*)&Bb[buf * 8192 + rl * 64], 16, 0, 0);
  };

  f32x4 acc[4][4];
#pragma unroll
  for (int mi = 0; mi < 4; ++mi)
#pragma unroll
    for (int ni = 0; ni < 4; ++ni) acc[mi][ni] = (f32x4){0.f, 0.f, 0.f, 0.f};

  // prologue: A(0) x4, B(0) x2, A(1) x4 -> 10 in flight
#pragma unroll
  for (int u = 0; u < 4; ++u) stageA(0, u, 0);
#pragma unroll
  for (int u = 0; u < 2; ++u) stageB(0, u, 0);
#pragma unroll
  for (int u = 0; u < 4; ++u) stageA(1, u, 1);

  for (int t = 0; t < NKT; ++t) {
    const int  ab   = t % 3;
    const int  bb   = t & 1;
    const bool preB = (t + 1) < NKT;
    const bool preA = (t + 2) < NKT;
    const int  ab2  = (t + 2) % 3;

    if (t < NKT - 1) asm volatile("s_waitcnt vmcnt(4)" ::: "memory");
    else             asm volatile("s_waitcnt vmcnt(0)" ::: "memory");
    __builtin_amdgcn_s_barrier();

    if (preB) { stageB(bb ^ 1, 0, t + 1); stageB(bb ^ 1, 1, t + 1); }
    if (preA) { stageA(ab2, 0, t + 2); stageA(ab2, 1, t + 2);
                stageA(ab2, 2, t + 2); stageA(ab2, 3, t + 2); }

#pragma unroll
    for (int ks = 0; ks < 2; ++ks) {
      const int gsw = ((ks * 4 + lg) ^ (lc & 7)) << 3;
      u16x8 bfr[4], af[4];
#pragma unroll
      for (int ni = 0; ni < 4; ++ni)
        bfr[ni] = *(const u16x8*)&Bb[bb * 8192 + (wn * 64 + ni * 16 + lc) * 64 + gsw];
#pragma unroll
      for (int i = 0; i < 4; ++i)
        af[i] = *(const u16x8*)&Ab[ab * 16384 + (wm * 64 + i * 16 + lc) * 64 + gsw];
#pragma unroll
      for (int i = 0; i < 4; ++i)
#pragma unroll
        for (int ni = 0; ni < 4; ++ni)
          acc[i][ni] = mfma_bf16(af[i], bfr[ni], acc[i][ni]);
    }
  }

  // epilogue (global only)
  const int gmb = row0 + wm * 64;
  const int gnb = col0 + wn * 64;
#pragma unroll
  for (int mi = 0; mi < 4; ++mi)
#pragma unroll
    for (int ni = 0; ni < 4; ++ni) {
      const int gm = gmb + mi * 16 + lg * 4;
      const int gn = gnb + ni * 16 + lc;
      const float bv = bias[gn];
      f32x4 v = acc[mi][ni];
#pragma unroll
      for (int r = 0; r < 4; ++r) C[(size_t)(gm + r) * 512 + gn] = v[r] + bv;
    }
}

// ---------------- launch ----------------
extern "C" void kernel_launch(void* const* d_in, const int* in_sizes, int n_in,
                              void* d_out, int out_size, void* d_ws, size_t ws_size,
                              hipStream_t stream) {
  const float* x        = (const float*)d_in[0];
  const float* pos_bias = (const float*)d_in[1];
  const float* Wq       = (const float*)d_in[2];
  const float* Wk       = (const float*)d_in[3];
  const float* Wv       = (const float*)d_in[4];
  const float* Wo       = (const float*)d_in[5];
  const float* bo       = (const float*)d_in[6];
  float* out            = (float*)d_out;

  u16* xb      = (u16*)d_ws;                           // [65536][512]
  u16* attnbuf = xb + (size_t)M_ROWS * 512;            // [65536][512]
  u16* Wo_t    = attnbuf + (size_t)M_ROWS * 512;       // [512][512]
  u16* Wqkv_t  = (u16*)d_out;                          // [1536][512] (dead until GEMM2)

  conv_x<<<dim3(M_ROWS * KDIM / (256 * 8)), dim3(256), 0, stream>>>(x, xb);
  convW_qkv_t<<<dim3(48, 16), dim3(256), 0, stream>>>(Wq, Wk, Wv, Wqkv_t);
  gemm_qkv_attn<<<dim3(4096), dim3(512), 0, stream>>>(xb, Wqkv_t, pos_bias, attnbuf);
  convWo_t<<<dim3(16, 16), dim3(256), 0, stream>>>(Wo, Wo_t);
  gemm_out<<<dim3(1024), dim3(512), 0, stream>>>(attnbuf, Wo_t, out, bo);
}